// Round 3
// baseline (4819.662 us; speedup 1.0000x reference)
//
#include <hip/hip_runtime.h>

// ---------------------------------------------------------------------------
// BiLSTM-CRF fused pipeline for MI355X (gfx950)
// B=64, S=512, V=50000, E=300, H=256 (H2=512), T=48
//   k_rec: 32 blocks = (NH=4 hidden) x (dir 2) x (GB=4 batch). W_hh register-
//   resident. Per-step h exchange via MALL with SELF-VALIDATING stores:
//   f32 h with step-tag ((t>>1)&1) in mantissa LSB, double-buffered on t&1.
//   No flags, no barriers: consumers poll exactly the words they consume.
// ---------------------------------------------------------------------------

using short8 = __attribute__((ext_vector_type(8))) short;
using f32x4  = __attribute__((ext_vector_type(4))) float;
typedef unsigned int  uint;
typedef unsigned short ushort;
typedef unsigned long long ull;

#define BATCH 64
#define SEQ   512
#define EMB   300
#define KPAD  320
#define HID   256
#define NTAG  48
#define NTOK  (BATCH*SEQ)          // 32768
#define T2STRIDE 60
#define GUARD_LIM (1<<18)

__device__ __forceinline__ float bf2f(ushort u) { return __uint_as_float(((uint)u) << 16); }
__device__ __forceinline__ ushort f2bf(float f) {
  uint u = __float_as_uint(f);
  return (ushort)((u + 0x7fffu + ((u >> 16) & 1u)) >> 16);   // RNE
}
__device__ __forceinline__ uint pk2(float a, float b) {
  return (uint)f2bf(a) | ((uint)f2bf(b) << 16);
}

// ---------------------------------------------------------------- prep kernels
__global__ void k_prep_wb(const float* __restrict__ wihf, const float* __restrict__ wihb,
                          ushort* __restrict__ wb) {
  int n = blockIdx.x;            // 0..2047
  int k = threadIdx.x;           // 0..319
  float v = 0.f;
  if (k < EMB) v = (n < 1024) ? wihf[n * EMB + k] : wihb[(n - 1024) * EMB + k];
  wb[n * KPAD + k] = f2bf(v);
}

// W_hh MFMA B-fragments (same layout as R2-verified version)
__global__ void k_prep_wfrag(const float* __restrict__ whhf, const float* __restrict__ whhb,
                             uint4* __restrict__ wfrag) {
  int flat = blockIdx.x * 256 + threadIdx.x;     // < 65536
  int l  = flat & 63;
  int kt = (flat >> 6) & 7;
  int g  = (flat >> 9) & 3;
  int w  = (flat >> 11) & 3;
  int nh = (flat >> 13) & 3;
  int dir = flat >> 15;
  const float* W = dir ? whhb : whhf;
  int unit = nh * 64 + w * 16 + (l & 15);
  int k0 = kt * 32 + (l >> 4) * 8;
  const float* wr = W + (size_t)(g * 256 + unit) * 256 + k0;
  uint4 o;
  o.x = pk2(wr[0], wr[1]); o.y = pk2(wr[2], wr[3]);
  o.z = pk2(wr[4], wr[5]); o.w = pk2(wr[6], wr[7]);
  wfrag[flat] = o;
}

__global__ void k_prep_wlt(const float* __restrict__ wlin, ushort* __restrict__ wltb) {
  int idx = blockIdx.x * 256 + threadIdx.x;   // < 32768
  int k = idx >> 6, j = idx & 63;
  wltb[idx] = f2bf((j < NTAG) ? wlin[j * 512 + k] : 0.f);
}

// hx tag-init: every uint LSB=1 (stale vs expected tags 0 at t=1/t=2).
// MANDATORY each launch: harness 0xAA poison has LSB 0 = false-valid.
__global__ void k_prep_hx(uint4* __restrict__ hx) {
  hx[blockIdx.x * 256 + threadIdx.x] = uint4{1u, 1u, 1u, 1u};
}

__global__ void k_prep_small(const float* __restrict__ bihf, const float* __restrict__ bhhf,
                             const float* __restrict__ bihb, const float* __restrict__ bhhb,
                             const float* __restrict__ trans,
                             float* __restrict__ bias, float* __restrict__ T2Tg,
                             float* __restrict__ cm2g, float* __restrict__ out) {
  int tid = threadIdx.x;
  if (tid == 0) out[0] = 0.f;
  for (int i = tid; i < 2048; i += 256)
    bias[i] = (i < 1024) ? (bihf[i] + bhhf[i]) : (bihb[i - 1024] + bhhb[i - 1024]);
  if (tid < NTAG) {
    const float L2E = 1.4426950408889634f;
    float cm = -3.0e38f;
    for (int i = 0; i < NTAG; ++i) cm = fmaxf(cm, trans[i * NTAG + tid] * L2E);
    cm2g[tid] = cm;
    for (int i = 0; i < NTAG; ++i)
      T2Tg[tid * T2STRIDE + i] = trans[i * NTAG + tid] * L2E - cm;
  }
}

// ---------------------------------------------------------------- gather
__global__ __launch_bounds__(256) void k_gather(const int* __restrict__ tok,
                                                const float* __restrict__ emb,
                                                ushort* __restrict__ xb) {
  int r = blockIdx.x * 4 + (threadIdx.x >> 6);   // token row, < 32768
  int l = threadIdx.x & 63;
  int t = tok[r];
  const float* e = emb + (size_t)t * EMB;
  ushort* xr = xb + (size_t)r * KPAD;
#pragma unroll
  for (int q = 0; q < 5; ++q) {
    int k = l + q * 64;
    xr[k] = f2bf((k < EMB) ? e[k] : 0.f);
  }
}

// ---------------------------------------------------------------- input-proj GEMM
// xproj layout: [m][dir*1024 + unit*4 + gate]  (gate-interleaved for k_rec)
__global__ __launch_bounds__(256) void k_gemm(const ushort* __restrict__ xb,
                                              const ushort* __restrict__ wb,
                                              const float* __restrict__ bias,
                                              ushort* __restrict__ xproj) {
  __shared__ __align__(16) ushort Asm[128 * 64];
  __shared__ __align__(16) ushort Bsm[128 * 64];
  const int tid = threadIdx.x;
  const int w = tid >> 6, l = tid & 63;
  const int m0 = blockIdx.y * 128, n0 = blockIdx.x * 128;
  const int wr = (w >> 1) * 64, wc = (w & 1) * 64;
  f32x4 acc[4][4] = {};

  for (int kt = 0; kt < 5; ++kt) {
    const int k0 = kt * 64;
    short8 va[4], vb[4];
#pragma unroll
    for (int i = 0; i < 4; ++i) {
      int cid = tid + 256 * i;
      int row = cid >> 3, slot = cid & 7;
      va[i] = *(const short8*)(xb + (size_t)(m0 + row) * KPAD + k0 + slot * 8);
      vb[i] = *(const short8*)(wb + (size_t)(n0 + row) * KPAD + k0 + slot * 8);
    }
    __syncthreads();
#pragma unroll
    for (int i = 0; i < 4; ++i) {
      int cid = tid + 256 * i;
      int row = cid >> 3, slot = cid & 7;
      int sw = (slot ^ (row & 7)) * 8;
      *(short8*)(&Asm[row * 64 + sw]) = va[i];
      *(short8*)(&Bsm[row * 64 + sw]) = vb[i];
    }
    __syncthreads();
#pragma unroll
    for (int kk = 0; kk < 2; ++kk) {
      int ks = (l >> 4) + kk * 4;
      short8 af[4], bfr[4];
#pragma unroll
      for (int mt = 0; mt < 4; ++mt) {
        int row = wr + mt * 16 + (l & 15);
        af[mt] = *(const short8*)(&Asm[row * 64 + ((ks ^ (row & 7)) * 8)]);
      }
#pragma unroll
      for (int nt = 0; nt < 4; ++nt) {
        int row = wc + nt * 16 + (l & 15);
        bfr[nt] = *(const short8*)(&Bsm[row * 64 + ((ks ^ (row & 7)) * 8)]);
      }
#pragma unroll
      for (int mt = 0; mt < 4; ++mt)
#pragma unroll
        for (int nt = 0; nt < 4; ++nt)
          acc[mt][nt] = __builtin_amdgcn_mfma_f32_16x16x32_bf16(af[mt], bfr[nt], acc[mt][nt], 0, 0, 0);
    }
  }
#pragma unroll
  for (int nt = 0; nt < 4; ++nt) {
    int n = n0 + wc + nt * 16 + (l & 15);
    float bv = bias[n];
    // remap column: n = dir*1024 + g*256 + unit  ->  dir*1024 + unit*4 + g
    int dirn = n >> 10, gn = (n >> 8) & 3, un = n & 255;
    size_t coff = (size_t)dirn * 1024 + un * 4 + gn;
#pragma unroll
    for (int mt = 0; mt < 4; ++mt) {
      int rbase = m0 + wr + mt * 16 + ((l >> 4) * 4);
#pragma unroll
      for (int r = 0; r < 4; ++r)
        xproj[(size_t)(rbase + r) * 2048 + coff] = f2bf(acc[mt][nt][r] + bv);
    }
  }
}

// ---------------------------------------------------------------- recurrent LSTM
// hx layout (uint = tagged f32): [grp 8][slot 2][row 16][unit 256]
__global__ __launch_bounds__(256) void k_rec(const ushort* __restrict__ xproj,
                                             const uint4* __restrict__ wfrag,
                                             ushort* __restrict__ hcat,
                                             uint* __restrict__ hx) {
  const int blk = blockIdx.x;
  const int nh = blk >> 3, dir = (blk >> 2) & 1, gb = blk & 3;
  const int tid = threadIdx.x, w = tid >> 6, l = tid & 63;
  const int grp = dir * 4 + gb;
  const int unit = nh * 64 + w * 16 + (l & 15);
  const int bb = gb * 16;
  const int rowq = (l >> 4) * 4;
  const int myrow = l & 15;
  // weights -> registers (128 VGPR/wave), once
  short8 wreg[4][8];
  {
    const uint4* wp = wfrag + (size_t)(dir * 16 + nh * 4 + w) * 2048 + l;
#pragma unroll
    for (int g = 0; g < 4; ++g)
#pragma unroll
      for (int kt = 0; kt < 8; ++kt) {
        union { uint4 u; short8 s; } cvt;
        cvt.u = wp[g * 512 + kt * 64];
        wreg[g][kt] = cvt.s;
      }
  }
  float c[4] = {0.f, 0.f, 0.f, 0.f};
  uint* hxg = hx + grp * 8192;
  int guard = 0;

  for (int t = 0; t < SEQ; ++t) {
    const int tt = dir ? (SEQ - 1 - t) : t;
    // xproj prefetch (independent of h) - one 8B load per row
    ull xq[4];
#pragma unroll
    for (int r = 0; r < 4; ++r) {
      const size_t m = (size_t)(bb + rowq + r) * SEQ + tt;
      xq[r] = *(const ull*)(xproj + m * 2048 + dir * 1024 + unit * 4);
    }
    f32x4 acc[4] = {};
    if (t > 0) {
      const uint rslot = (uint)((t - 1) & 1) * 4096u;
      const uint expTag = (uint)(((t - 1) >> 1) & 1);
      const ull expPair = (ull)expTag * 0x0000000100000001ull;
      const ull* base = (const ull*)(hxg + rslot) + myrow * 128 + (l >> 4) * 4;
      short8 af[8];
      for (;;) {
        ull bad = 0;
#pragma unroll
        for (int kt = 0; kt < 8; ++kt) {
          const ull* p = base + kt * 16;
          ull v0 = __hip_atomic_load(p,     __ATOMIC_RELAXED, __HIP_MEMORY_SCOPE_AGENT);
          ull v1 = __hip_atomic_load(p + 1, __ATOMIC_RELAXED, __HIP_MEMORY_SCOPE_AGENT);
          ull v2 = __hip_atomic_load(p + 2, __ATOMIC_RELAXED, __HIP_MEMORY_SCOPE_AGENT);
          ull v3 = __hip_atomic_load(p + 3, __ATOMIC_RELAXED, __HIP_MEMORY_SCOPE_AGENT);
          bad |= (v0 ^ expPair) | (v1 ^ expPair) | (v2 ^ expPair) | (v3 ^ expPair);
          union { uint u[4]; short8 s; } pk;
          pk.u[0] = __builtin_amdgcn_perm((uint)(v0 >> 32), (uint)v0, 0x07060302u);
          pk.u[1] = __builtin_amdgcn_perm((uint)(v1 >> 32), (uint)v1, 0x07060302u);
          pk.u[2] = __builtin_amdgcn_perm((uint)(v2 >> 32), (uint)v2, 0x07060302u);
          pk.u[3] = __builtin_amdgcn_perm((uint)(v3 >> 32), (uint)v3, 0x07060302u);
          af[kt] = pk.s;
        }
        bad &= 0x0000000100000001ull;
        if (bad == 0) break;
        if (++guard > GUARD_LIM) break;     // fail-fast, never hang
        __builtin_amdgcn_s_sleep(1);
      }
#pragma unroll
      for (int g = 0; g < 4; ++g)
#pragma unroll
        for (int kt = 0; kt < 8; ++kt)
          acc[g] = __builtin_amdgcn_mfma_f32_16x16x32_bf16(af[kt], wreg[g][kt], acc[g], 0, 0, 0);
    }
    const uint wslot = (uint)(t & 1) * 4096u;
    const uint wtag = (uint)((t >> 1) & 1);
#pragma unroll
    for (int r = 0; r < 4; ++r) {
      float zi = acc[0][r] + bf2f((ushort)(xq[r]));
      float zf = acc[1][r] + bf2f((ushort)(xq[r] >> 16));
      float zg = acc[2][r] + bf2f((ushort)(xq[r] >> 32));
      float zo = acc[3][r] + bf2f((ushort)(xq[r] >> 48));
      float ig = 1.f / (1.f + __expf(-zi));
      float fg = 1.f / (1.f + __expf(-zf));
      float gg = 2.f / (1.f + __expf(-2.f * zg)) - 1.f;
      float og = 1.f / (1.f + __expf(-zo));
      c[r] = fg * c[r] + ig * gg;
      float hv = og * (2.f / (1.f + __expf(-2.f * c[r])) - 1.f);
      // exchange store FIRST (critical path), tagged f32
      uint hu = (__float_as_uint(hv) & ~1u) | wtag;
      __hip_atomic_store(hxg + wslot + (uint)(rowq + r) * 256u + (uint)unit, hu,
                         __ATOMIC_RELAXED, __HIP_MEMORY_SCOPE_AGENT);
      const size_t m = (size_t)(bb + rowq + r) * SEQ + tt;
      hcat[m * 512 + dir * 256 + unit] = f2bf(hv);
    }
  }
}

// ---------------------------------------------------------------- output linear
__global__ __launch_bounds__(256) void k_lin(const ushort* __restrict__ hcat,
                                             const ushort* __restrict__ wltb,
                                             const float* __restrict__ blin,
                                             float* __restrict__ logits) {
  __shared__ __align__(16) ushort wsm[512 * 64];
  const int tid = threadIdx.x;
#pragma unroll
  for (int i = 0; i < 16; ++i)
    ((short8*)wsm)[tid + 256 * i] = ((const short8*)wltb)[tid + 256 * i];
  __syncthreads();
  const int w = tid >> 6, l = tid & 63;
  float blv = (l < NTAG) ? blin[l] : 0.f;
  for (int q = 0; q < 4; ++q) {
    size_t m = (size_t)blockIdx.x * 16 + w * 4 + q;
    const ushort* hp = hcat + m * 512;
    float acc = blv;
#pragma unroll 2
    for (int k8 = 0; k8 < 64; ++k8) {
      short8 hv = *(const short8*)(hp + k8 * 8);
#pragma unroll
      for (int kk = 0; kk < 8; ++kk)
        acc += bf2f((ushort)hv[kk]) * bf2f(wsm[(k8 * 8 + kk) * 64 + l]);
    }
    if (l < NTAG) logits[m * NTAG + l] = acc;
  }
}

// ---------------------------------------------------------------- CRF
__global__ __launch_bounds__(64) void k_crf(const float* __restrict__ logits,
                                            const int* __restrict__ labels,
                                            const int* __restrict__ slen,
                                            const float* __restrict__ trans,
                                            const float* __restrict__ startt,
                                            const float* __restrict__ endt,
                                            const float* __restrict__ T2Tg,
                                            const float* __restrict__ cm2g,
                                            float* __restrict__ out) {
  __shared__ float Ttab[NTAG * NTAG];
  __shared__ __align__(16) float T2T[NTAG * T2STRIDE];
  __shared__ __align__(16) float As[64];
  __shared__ float cm2[NTAG];
  const int b = blockIdx.x, l = threadIdx.x;
  for (int i = l; i < NTAG * NTAG; i += 64) Ttab[i] = trans[i];
  for (int i = l; i < NTAG * T2STRIDE; i += 64) T2T[i] = T2Tg[i];
  if (l < NTAG) cm2[l] = cm2g[l];
  __syncthreads();
  const float L2E = 1.4426950408889634f;
  const float LN2 = 0.6931471805599453f;
  int len = slen[b]; len = (len < 1) ? 1 : (len > SEQ ? SEQ : len);
  float A = -3.0e38f;
  float score = 0.f;
  int prevtag = 0, lasttag = 0;
  float myend = (l < NTAG) ? endt[l] : 0.f;
  float cmv   = (l < NTAG) ? cm2[l] : 0.f;

  for (int t = 0; t < SEQ; ++t) {
    const float* lg = logits + ((size_t)b * SEQ + t) * NTAG;
    float lv = (l < NTAG) ? lg[l] : -3.0e38f;
    float mx = lv;
#pragma unroll
    for (int s = 32; s; s >>= 1) mx = fmaxf(mx, __shfl_xor(mx, s));
    float e = (l < NTAG) ? exp2f((lv - mx) * L2E) : 0.f;
    float ssum = e;
#pragma unroll
    for (int s = 32; s; s >>= 1) ssum += __shfl_xor(ssum, s);
    float p = e / ssum;
    int tag = labels[(size_t)b * SEQ + t];
    float ptag = __shfl(p, tag);
    if (t == 0) {
      A = (l < NTAG) ? (startt[l] + p) * L2E : -3.0e38f;
      score = startt[tag] + ptag;
      prevtag = tag; lasttag = tag;
    } else if (t < len) {
      float amax = (l < NTAG) ? A : -3.0e38f;
#pragma unroll
      for (int s = 32; s; s >>= 1) amax = fmaxf(amax, __shfl_xor(amax, s));
      As[l] = A - amax;
      __syncthreads();
      if (l < NTAG) {
        float acc2 = 0.f;
#pragma unroll 3
        for (int ic = 0; ic < 12; ++ic) {
          float4 av = *(const float4*)&As[ic * 4];
          float4 tv = *(const float4*)&T2T[l * T2STRIDE + ic * 4];
          acc2 += exp2f(av.x + tv.x);
          acc2 += exp2f(av.y + tv.y);
          acc2 += exp2f(av.z + tv.z);
          acc2 += exp2f(av.w + tv.w);
        }
        A = amax + cmv + log2f(acc2) + p * L2E;
      }
      __syncthreads();
      score += Ttab[prevtag * NTAG + tag] + ptag;
      prevtag = tag; lasttag = tag;
    }
  }
  score += endt[lasttag];
  float v = (l < NTAG) ? (A + myend * L2E) : -3.0e38f;
  float M = v;
#pragma unroll
  for (int s = 32; s; s >>= 1) M = fmaxf(M, __shfl_xor(M, s));
  float sz = (l < NTAG) ? exp2f(v - M) : 0.f;
#pragma unroll
  for (int s = 32; s; s >>= 1) sz += __shfl_xor(sz, s);
  float logz = (M + log2f(sz)) * LN2;
  if (l == 0) atomicAdd(out, logz - score);
}

// ---------------------------------------------------------------- launch
extern "C" void kernel_launch(void* const* d_in, const int* in_sizes, int n_in,
                              void* d_out, int out_size, void* d_ws, size_t ws_size,
                              hipStream_t stream) {
  const int*   tok    = (const int*)d_in[0];
  const int*   slen   = (const int*)d_in[1];
  const int*   lab    = (const int*)d_in[2];
  const float* emb    = (const float*)d_in[3];
  const float* wihf   = (const float*)d_in[4];
  const float* whhf   = (const float*)d_in[5];
  const float* bihf   = (const float*)d_in[6];
  const float* bhhf   = (const float*)d_in[7];
  const float* wihb   = (const float*)d_in[8];
  const float* whhb   = (const float*)d_in[9];
  const float* bihb   = (const float*)d_in[10];
  const float* bhhb   = (const float*)d_in[11];
  const float* wlin   = (const float*)d_in[12];
  const float* blin   = (const float*)d_in[13];
  const float* trans  = (const float*)d_in[14];
  const float* startt = (const float*)d_in[15];
  const float* endt   = (const float*)d_in[16];
  float* out = (float*)d_out;

  char* p = (char*)d_ws;
  ushort* xproj = (ushort*)p; p += (size_t)NTOK * 2048 * 2;     // 134 MB
  ushort* xb    = (ushort*)p; p += (size_t)NTOK * KPAD * 2;     // 21 MB
  ushort* wb    = (ushort*)p; p += (size_t)2048 * KPAD * 2;     // 1.3 MB
  uint4*  wfrag = (uint4*)p;  p += (size_t)65536 * 16;          // 1 MB
  ushort* hcat  = (ushort*)p; p += (size_t)NTOK * 512 * 2;      // 33.5 MB
  float*  logit = (float*)p;  p += (size_t)NTOK * NTAG * 4;     // 6.3 MB
  ushort* wltb  = (ushort*)p; p += (size_t)32768 * 2;           // 64 KB
  float*  bias  = (float*)p;  p += 2048 * 4;
  float*  T2Tg  = (float*)p;  p += (size_t)NTAG * T2STRIDE * 4;
  float*  cm2g  = (float*)p;  p += 256;
  uint*   hx    = (uint*)p;   p += (size_t)65536 * 4;           // 256 KB tagged h exchange

  k_prep_wb   <<<2048, 320, 0, stream>>>(wihf, wihb, wb);
  k_prep_wfrag<<<256, 256, 0, stream>>>(whhf, whhb, wfrag);
  k_prep_wlt  <<<128, 256, 0, stream>>>(wlin, wltb);
  k_prep_hx   <<<64, 256, 0, stream>>>((uint4*)hx);
  k_prep_small<<<1, 256, 0, stream>>>(bihf, bhhf, bihb, bhhb, trans, bias, T2Tg, cm2g, out);
  k_gather    <<<NTOK / 4, 256, 0, stream>>>(tok, emb, xb);
  k_gemm      <<<dim3(16, 256), 256, 0, stream>>>(xb, wb, bias, xproj);
  k_rec       <<<32, 256, 0, stream>>>(xproj, wfrag, hcat, hx);
  k_lin       <<<NTOK / 16, 256, 0, stream>>>(hcat, wltb, blin, logit);
  k_crf       <<<BATCH, 64, 0, stream>>>(logit, lab, slen, trans, startt, endt, T2Tg, cm2g, out);
}

// Round 4
// 3457.570 us; speedup vs baseline: 1.3939x; 1.3939x over previous
//
#include <hip/hip_runtime.h>

// ---------------------------------------------------------------------------
// BiLSTM-CRF fused pipeline for MI355X (gfx950)
// B=64, S=512, V=50000, E=300, H=256 (H2=512), T=48
//   k_rec v3: 16 blocks = (dir 2) x (batch-chunk 8 of 8 rows), 512 threads.
//   W_hh quantized to i8 (per gate-row scale), resident in VGPRs
//   (128/wave x 8 waves = full direction). h i8 in LDS, double-buffered,
//   16B-granule XOR swizzle. NO cross-block sync of any kind.
// ---------------------------------------------------------------------------

using short8 = __attribute__((ext_vector_type(8))) short;
using f32x4  = __attribute__((ext_vector_type(4))) float;
using i32x4  = __attribute__((ext_vector_type(4))) int;
typedef unsigned int  uint;
typedef unsigned short ushort;
typedef unsigned long long ull;

#define BATCH 64
#define SEQ   512
#define EMB   300
#define KPAD  320
#define HID   256
#define NTAG  48
#define NTOK  (BATCH*SEQ)          // 32768
#define T2STRIDE 60

__device__ __forceinline__ float bf2f(ushort u) { return __uint_as_float(((uint)u) << 16); }
__device__ __forceinline__ ushort f2bf(float f) {
  uint u = __float_as_uint(f);
  return (ushort)((u + 0x7fffu + ((u >> 16) & 1u)) >> 16);   // RNE
}
__device__ __forceinline__ uint pk2(float a, float b) {
  return (uint)f2bf(a) | ((uint)f2bf(b) << 16);
}

// ---------------------------------------------------------------- prep kernels
__global__ void k_prep_wb(const float* __restrict__ wihf, const float* __restrict__ wihb,
                          ushort* __restrict__ wb) {
  int n = blockIdx.x;            // 0..2047
  int k = threadIdx.x;           // 0..319
  float v = 0.f;
  if (k < EMB) v = (n < 1024) ? wihf[n * EMB + k] : wihb[(n - 1024) * EMB + k];
  wb[n * KPAD + k] = f2bf(v);
}

// W_hh -> i8 rows + per-row dequant scale (includes s_h = 1/127)
__global__ void k_prep_qw(const float* __restrict__ whhf, const float* __restrict__ whhb,
                          uint* __restrict__ wq, float* __restrict__ qscale) {
  int bx = blockIdx.x;           // 0..2047
  int dir = bx >> 10, n = bx & 1023;
  int l = threadIdx.x;           // 0..63
  const float* W = (dir ? whhb : whhf) + (size_t)n * 256 + l * 4;
  float w0 = W[0], w1 = W[1], w2 = W[2], w3 = W[3];
  float mx = fmaxf(fmaxf(fabsf(w0), fabsf(w1)), fmaxf(fabsf(w2), fabsf(w3)));
#pragma unroll
  for (int s = 32; s; s >>= 1) mx = fmaxf(mx, __shfl_xor(mx, s));
  mx = fmaxf(mx, 1e-30f);
  float inv = 127.f / mx;
  if (l == 0) qscale[dir * 1024 + n] = mx * (1.f / 16129.f);   // (mx/127)*(1/127)
  int q0 = (int)rintf(w0 * inv), q1 = (int)rintf(w1 * inv);
  int q2 = (int)rintf(w2 * inv), q3 = (int)rintf(w3 * inv);
  uint b = ((uint)q0 & 0xffu) | (((uint)q1 & 0xffu) << 8) |
           (((uint)q2 & 0xffu) << 16) | (((uint)q3 & 0xffu) << 24);
  wq[(size_t)(dir * 1024 + n) * 64 + l] = b;
}

// gather i8 rows into MFMA B-fragments:
// flat = (((dir*8 + w)*8 + tile)*4 + kc)*64 + lane ; tile = g*2+uh
// col n = g*256 + w*32 + uh*16 + (lane&15); k = kc*64 + (lane>>4)*16 + 0..15
__global__ void k_prep_wfrag8(const uint* __restrict__ wq, uint4* __restrict__ wfrag8) {
  int flat = blockIdx.x * 256 + threadIdx.x;   // < 32768
  int lane = flat & 63;
  int kc   = (flat >> 6) & 3;
  int tile = (flat >> 8) & 7;
  int w    = (flat >> 11) & 7;
  int dir  = flat >> 14;
  int g = tile >> 1, uh = tile & 1;
  int n = g * 256 + w * 32 + uh * 16 + (lane & 15);
  int k0 = kc * 64 + ((lane >> 4) & 3) * 16;
  const uint4* src = (const uint4*)(wq + (size_t)(dir * 1024 + n) * 64 + k0 / 4);
  wfrag8[flat] = *src;
}

__global__ void k_prep_wlt(const float* __restrict__ wlin, ushort* __restrict__ wltb) {
  int idx = blockIdx.x * 256 + threadIdx.x;   // < 32768
  int k = idx >> 6, j = idx & 63;
  wltb[idx] = f2bf((j < NTAG) ? wlin[j * 512 + k] : 0.f);
}

__global__ void k_prep_small(const float* __restrict__ bihf, const float* __restrict__ bhhf,
                             const float* __restrict__ bihb, const float* __restrict__ bhhb,
                             const float* __restrict__ trans,
                             float* __restrict__ bias, float* __restrict__ T2Tg,
                             float* __restrict__ cm2g, float* __restrict__ out) {
  int tid = threadIdx.x;
  if (tid == 0) out[0] = 0.f;
  for (int i = tid; i < 2048; i += 256)
    bias[i] = (i < 1024) ? (bihf[i] + bhhf[i]) : (bihb[i - 1024] + bhhb[i - 1024]);
  if (tid < NTAG) {
    const float L2E = 1.4426950408889634f;
    float cm = -3.0e38f;
    for (int i = 0; i < NTAG; ++i) cm = fmaxf(cm, trans[i * NTAG + tid] * L2E);
    cm2g[tid] = cm;
    for (int i = 0; i < NTAG; ++i)
      T2Tg[tid * T2STRIDE + i] = trans[i * NTAG + tid] * L2E - cm;
  }
}

// ---------------------------------------------------------------- gather
__global__ __launch_bounds__(256) void k_gather(const int* __restrict__ tok,
                                                const float* __restrict__ emb,
                                                ushort* __restrict__ xb) {
  int r = blockIdx.x * 4 + (threadIdx.x >> 6);   // token row, < 32768
  int l = threadIdx.x & 63;
  int t = tok[r];
  const float* e = emb + (size_t)t * EMB;
  ushort* xr = xb + (size_t)r * KPAD;
#pragma unroll
  for (int q = 0; q < 5; ++q) {
    int k = l + q * 64;
    xr[k] = f2bf((k < EMB) ? e[k] : 0.f);
  }
}

// ---------------------------------------------------------------- input-proj GEMM
// xproj layout: [m][dir*1024 + unit*4 + gate]  (gate-interleaved for k_rec)
__global__ __launch_bounds__(256) void k_gemm(const ushort* __restrict__ xb,
                                              const ushort* __restrict__ wb,
                                              const float* __restrict__ bias,
                                              ushort* __restrict__ xproj) {
  __shared__ __align__(16) ushort Asm[128 * 64];
  __shared__ __align__(16) ushort Bsm[128 * 64];
  const int tid = threadIdx.x;
  const int w = tid >> 6, l = tid & 63;
  const int m0 = blockIdx.y * 128, n0 = blockIdx.x * 128;
  const int wr = (w >> 1) * 64, wc = (w & 1) * 64;
  f32x4 acc[4][4] = {};

  for (int kt = 0; kt < 5; ++kt) {
    const int k0 = kt * 64;
    short8 va[4], vb[4];
#pragma unroll
    for (int i = 0; i < 4; ++i) {
      int cid = tid + 256 * i;
      int row = cid >> 3, slot = cid & 7;
      va[i] = *(const short8*)(xb + (size_t)(m0 + row) * KPAD + k0 + slot * 8);
      vb[i] = *(const short8*)(wb + (size_t)(n0 + row) * KPAD + k0 + slot * 8);
    }
    __syncthreads();
#pragma unroll
    for (int i = 0; i < 4; ++i) {
      int cid = tid + 256 * i;
      int row = cid >> 3, slot = cid & 7;
      int sw = (slot ^ (row & 7)) * 8;
      *(short8*)(&Asm[row * 64 + sw]) = va[i];
      *(short8*)(&Bsm[row * 64 + sw]) = vb[i];
    }
    __syncthreads();
#pragma unroll
    for (int kk = 0; kk < 2; ++kk) {
      int ks = (l >> 4) + kk * 4;
      short8 af[4], bfr[4];
#pragma unroll
      for (int mt = 0; mt < 4; ++mt) {
        int row = wr + mt * 16 + (l & 15);
        af[mt] = *(const short8*)(&Asm[row * 64 + ((ks ^ (row & 7)) * 8)]);
      }
#pragma unroll
      for (int nt = 0; nt < 4; ++nt) {
        int row = wc + nt * 16 + (l & 15);
        bfr[nt] = *(const short8*)(&Bsm[row * 64 + ((ks ^ (row & 7)) * 8)]);
      }
#pragma unroll
      for (int mt = 0; mt < 4; ++mt)
#pragma unroll
        for (int nt = 0; nt < 4; ++nt)
          acc[mt][nt] = __builtin_amdgcn_mfma_f32_16x16x32_bf16(af[mt], bfr[nt], acc[mt][nt], 0, 0, 0);
    }
  }
#pragma unroll
  for (int nt = 0; nt < 4; ++nt) {
    int n = n0 + wc + nt * 16 + (l & 15);
    float bv = bias[n];
    int dirn = n >> 10, gn = (n >> 8) & 3, un = n & 255;
    size_t coff = (size_t)dirn * 1024 + un * 4 + gn;
#pragma unroll
    for (int mt = 0; mt < 4; ++mt) {
      int rbase = m0 + wr + mt * 16 + ((l >> 4) * 4);
#pragma unroll
      for (int r = 0; r < 4; ++r)
        xproj[(size_t)(rbase + r) * 2048 + coff] = f2bf(acc[mt][nt][r] + bv);
    }
  }
}

// ---------------------------------------------------------------- recurrent LSTM
// block = (dir, batch-chunk of 8). 8 waves; wave w owns units [w*32,+32) x 4 gates.
__global__ __launch_bounds__(512, 2) void k_rec(const ushort* __restrict__ xproj,
                                                const uint4* __restrict__ wfrag8,
                                                const float* __restrict__ qscale,
                                                ushort* __restrict__ hcat) {
  const int blk = blockIdx.x;
  const int dir = blk & 1, chunk = blk >> 1;
  const int bb = chunk * 8;
  const int tid = threadIdx.x, w = tid >> 6, l = tid & 63;
  const int rbase = (l >> 4) * 4;          // D-row base (batch-local)
  const int lu = l & 15;
  __shared__ __align__(16) char hlds[2 * 16 * 256];   // [slot][row][unit] i8, granule-swizzled

  // W_hh i8 B-frags -> 128 VGPR, once
  i32x4 wfr[8][4];
  {
    const uint4* wp = wfrag8 + (size_t)(dir * 8 + w) * 2048 + l;
#pragma unroll
    for (int tile = 0; tile < 8; ++tile)
#pragma unroll
      for (int kc = 0; kc < 4; ++kc) {
        union { uint4 u; i32x4 v; } cc;
        cc.u = wp[tile * 256 + kc * 64];
        wfr[tile][kc] = cc.v;
      }
  }
  float qs[4][2];
#pragma unroll
  for (int g = 0; g < 4; ++g)
#pragma unroll
    for (int uh = 0; uh < 2; ++uh)
      qs[g][uh] = qscale[dir * 1024 + g * 256 + w * 32 + uh * 16 + lu];

  const int tt0 = dir ? (SEQ - 1) : 0;
  const ptrdiff_t dstep = dir ? -2048 : 2048;
  const ushort* pq[4];
#pragma unroll
  for (int q = 0; q < 4; ++q)
    pq[q] = xproj + ((size_t)(bb + rbase + q) * SEQ + tt0) * 2048 + dir * 1024 + (w * 32 + lu) * 4;

  float c[2][4] = {};
  int tt = tt0;

  for (int t = 0; t < SEQ; ++t) {
    ull xc[2][4];
    if (l < 32) {                 // rows 0..7 valid only
#pragma unroll
      for (int uh = 0; uh < 2; ++uh)
#pragma unroll
        for (int q = 0; q < 4; ++q)
          xc[uh][q] = *(const ull*)(pq[q] + uh * 64);
    }
    i32x4 acc[8] = {};
    if (t > 0) {
      const int rs = (t - 1) & 1;
      i32x4 a[4];
#pragma unroll
      for (int kc = 0; kc < 4; ++kc) {
        int lg = kc * 4 + (l >> 4);
        int phys = lg ^ lu;
        a[kc] = *(const i32x4*)(&hlds[rs * 4096 + lu * 256 + phys * 16]);
      }
#pragma unroll
      for (int tile = 0; tile < 8; ++tile)
#pragma unroll
        for (int kc = 0; kc < 4; ++kc)
          acc[tile] = __builtin_amdgcn_mfma_i32_16x16x64_i8(a[kc], wfr[tile][kc], acc[tile], 0, 0, 0);
    }
    if (l < 32) {
      const int wslot = t & 1;
      const size_t hoff0 = ((size_t)(bb + rbase) * SEQ + tt) * 512 + dir * 256;
#pragma unroll
      for (int uh = 0; uh < 2; ++uh) {
        const int unit = w * 32 + uh * 16 + lu;
        uint hv8 = 0;
#pragma unroll
        for (int q = 0; q < 4; ++q) {
          float zi = (float)acc[0 + uh][q] * qs[0][uh] + bf2f((ushort)(xc[uh][q]));
          float zf = (float)acc[2 + uh][q] * qs[1][uh] + bf2f((ushort)(xc[uh][q] >> 16));
          float zg = (float)acc[4 + uh][q] * qs[2][uh] + bf2f((ushort)(xc[uh][q] >> 32));
          float zo = (float)acc[6 + uh][q] * qs[3][uh] + bf2f((ushort)(xc[uh][q] >> 48));
          float ig = 1.f / (1.f + __expf(-zi));
          float fg = 1.f / (1.f + __expf(-zf));
          float gg = 2.f / (1.f + __expf(-2.f * zg)) - 1.f;
          float og = 1.f / (1.f + __expf(-zo));
          c[uh][q] = fg * c[uh][q] + ig * gg;
          float hv = og * (2.f / (1.f + __expf(-2.f * c[uh][q])) - 1.f);
          hcat[hoff0 + (size_t)q * (SEQ * 512) + unit] = f2bf(hv);
          int hq = (int)rintf(hv * 127.f);
          hv8 |= ((uint)hq & 0xffu) << (8 * q);
        }
        // 4x4 byte transpose across quad lanes: byte q (row) -> lane (l&3)
        uint x1 = __shfl_xor(hv8, 1);
        uint s1 = (l & 1) ? 0x03070105u : 0x06020400u;
        uint wv = __builtin_amdgcn_perm(x1, hv8, s1);
        uint x2 = __shfl_xor(wv, 2);
        uint s2 = (l & 2) ? 0x03020706u : 0x05040100u;
        uint u = __builtin_amdgcn_perm(x2, wv, s2);
        const int row = rbase + (l & 3);
        const int physw = (w * 2 + uh) ^ row;
        *(uint*)(&hlds[wslot * 4096 + row * 256 + physw * 16 + (l & 12)]) = u;
      }
    }
    __syncthreads();
#pragma unroll
    for (int q = 0; q < 4; ++q) pq[q] += dstep;
    tt += dir ? -1 : 1;
  }
}

// ---------------------------------------------------------------- output linear
__global__ __launch_bounds__(256) void k_lin(const ushort* __restrict__ hcat,
                                             const ushort* __restrict__ wltb,
                                             const float* __restrict__ blin,
                                             float* __restrict__ logits) {
  __shared__ __align__(16) ushort wsm[512 * 64];
  const int tid = threadIdx.x;
#pragma unroll
  for (int i = 0; i < 16; ++i)
    ((short8*)wsm)[tid + 256 * i] = ((const short8*)wltb)[tid + 256 * i];
  __syncthreads();
  const int w = tid >> 6, l = tid & 63;
  float blv = (l < NTAG) ? blin[l] : 0.f;
  for (int q = 0; q < 4; ++q) {
    size_t m = (size_t)blockIdx.x * 16 + w * 4 + q;
    const ushort* hp = hcat + m * 512;
    float acc = blv;
#pragma unroll 2
    for (int k8 = 0; k8 < 64; ++k8) {
      short8 hv = *(const short8*)(hp + k8 * 8);
#pragma unroll
      for (int kk = 0; kk < 8; ++kk)
        acc += bf2f((ushort)hv[kk]) * bf2f(wsm[(k8 * 8 + kk) * 64 + l]);
    }
    if (l < NTAG) logits[m * NTAG + l] = acc;
  }
}

// ---------------------------------------------------------------- CRF
__global__ __launch_bounds__(64) void k_crf(const float* __restrict__ logits,
                                            const int* __restrict__ labels,
                                            const int* __restrict__ slen,
                                            const float* __restrict__ trans,
                                            const float* __restrict__ startt,
                                            const float* __restrict__ endt,
                                            const float* __restrict__ T2Tg,
                                            const float* __restrict__ cm2g,
                                            float* __restrict__ out) {
  __shared__ float Ttab[NTAG * NTAG];
  __shared__ __align__(16) float T2T[NTAG * T2STRIDE];
  __shared__ __align__(16) float As[64];
  __shared__ float cm2[NTAG];
  const int b = blockIdx.x, l = threadIdx.x;
  for (int i = l; i < NTAG * NTAG; i += 64) Ttab[i] = trans[i];
  for (int i = l; i < NTAG * T2STRIDE; i += 64) T2T[i] = T2Tg[i];
  if (l < NTAG) cm2[l] = cm2g[l];
  __syncthreads();
  const float L2E = 1.4426950408889634f;
  const float LN2 = 0.6931471805599453f;
  int len = slen[b]; len = (len < 1) ? 1 : (len > SEQ ? SEQ : len);
  float A = -3.0e38f;
  float score = 0.f;
  int prevtag = 0, lasttag = 0;
  float myend = (l < NTAG) ? endt[l] : 0.f;
  float cmv   = (l < NTAG) ? cm2[l] : 0.f;

  for (int t = 0; t < SEQ; ++t) {
    const float* lg = logits + ((size_t)b * SEQ + t) * NTAG;
    float lv = (l < NTAG) ? lg[l] : -3.0e38f;
    float mx = lv;
#pragma unroll
    for (int s = 32; s; s >>= 1) mx = fmaxf(mx, __shfl_xor(mx, s));
    float e = (l < NTAG) ? exp2f((lv - mx) * L2E) : 0.f;
    float ssum = e;
#pragma unroll
    for (int s = 32; s; s >>= 1) ssum += __shfl_xor(ssum, s);
    float p = e / ssum;
    int tag = labels[(size_t)b * SEQ + t];
    float ptag = __shfl(p, tag);
    if (t == 0) {
      A = (l < NTAG) ? (startt[l] + p) * L2E : -3.0e38f;
      score = startt[tag] + ptag;
      prevtag = tag; lasttag = tag;
    } else if (t < len) {
      float amax = (l < NTAG) ? A : -3.0e38f;
#pragma unroll
      for (int s = 32; s; s >>= 1) amax = fmaxf(amax, __shfl_xor(amax, s));
      As[l] = A - amax;
      __syncthreads();
      if (l < NTAG) {
        float acc2 = 0.f;
#pragma unroll 3
        for (int ic = 0; ic < 12; ++ic) {
          float4 av = *(const float4*)&As[ic * 4];
          float4 tv = *(const float4*)&T2T[l * T2STRIDE + ic * 4];
          acc2 += exp2f(av.x + tv.x);
          acc2 += exp2f(av.y + tv.y);
          acc2 += exp2f(av.z + tv.z);
          acc2 += exp2f(av.w + tv.w);
        }
        A = amax + cmv + log2f(acc2) + p * L2E;
      }
      __syncthreads();
      score += Ttab[prevtag * NTAG + tag] + ptag;
      prevtag = tag; lasttag = tag;
    }
  }
  score += endt[lasttag];
  float v = (l < NTAG) ? (A + myend * L2E) : -3.0e38f;
  float M = v;
#pragma unroll
  for (int s = 32; s; s >>= 1) M = fmaxf(M, __shfl_xor(M, s));
  float sz = (l < NTAG) ? exp2f(v - M) : 0.f;
#pragma unroll
  for (int s = 32; s; s >>= 1) sz += __shfl_xor(sz, s);
  float logz = (M + log2f(sz)) * LN2;
  if (l == 0) atomicAdd(out, logz - score);
}

// ---------------------------------------------------------------- launch
extern "C" void kernel_launch(void* const* d_in, const int* in_sizes, int n_in,
                              void* d_out, int out_size, void* d_ws, size_t ws_size,
                              hipStream_t stream) {
  const int*   tok    = (const int*)d_in[0];
  const int*   slen   = (const int*)d_in[1];
  const int*   lab    = (const int*)d_in[2];
  const float* emb    = (const float*)d_in[3];
  const float* wihf   = (const float*)d_in[4];
  const float* whhf   = (const float*)d_in[5];
  const float* bihf   = (const float*)d_in[6];
  const float* bhhf   = (const float*)d_in[7];
  const float* wihb   = (const float*)d_in[8];
  const float* whhb   = (const float*)d_in[9];
  const float* bihb   = (const float*)d_in[10];
  const float* bhhb   = (const float*)d_in[11];
  const float* wlin   = (const float*)d_in[12];
  const float* blin   = (const float*)d_in[13];
  const float* trans  = (const float*)d_in[14];
  const float* startt = (const float*)d_in[15];
  const float* endt   = (const float*)d_in[16];
  float* out = (float*)d_out;

  char* p = (char*)d_ws;
  ushort* xproj  = (ushort*)p; p += (size_t)NTOK * 2048 * 2;     // 134 MB
  ushort* xb     = (ushort*)p; p += (size_t)NTOK * KPAD * 2;     // 21 MB
  ushort* wb     = (ushort*)p; p += (size_t)2048 * KPAD * 2;     // 1.3 MB
  ushort* hcat   = (ushort*)p; p += (size_t)NTOK * 512 * 2;      // 33.5 MB
  float*  logit  = (float*)p;  p += (size_t)NTOK * NTAG * 4;     // 6.3 MB
  ushort* wltb   = (ushort*)p; p += (size_t)32768 * 2;           // 64 KB
  float*  bias   = (float*)p;  p += 2048 * 4;
  float*  T2Tg   = (float*)p;  p += (size_t)NTAG * T2STRIDE * 4;
  float*  cm2g   = (float*)p;  p += 256;
  uint*   wq     = (uint*)p;   p += (size_t)2048 * 64 * 4;       // 512 KB i8 W_hh rows
  uint4*  wfrag8 = (uint4*)p;  p += (size_t)32768 * 16;          // 512 KB i8 B-frags
  float*  qscale = (float*)p;  p += 2048 * 4;                    // 8 KB

  k_prep_wb    <<<2048, 320, 0, stream>>>(wihf, wihb, wb);
  k_prep_qw    <<<2048, 64, 0, stream>>>(whhf, whhb, wq, qscale);
  k_prep_wfrag8<<<128, 256, 0, stream>>>(wq, wfrag8);
  k_prep_wlt   <<<128, 256, 0, stream>>>(wlin, wltb);
  k_prep_small <<<1, 256, 0, stream>>>(bihf, bhhf, bihb, bhhb, trans, bias, T2Tg, cm2g, out);
  k_gather     <<<NTOK / 4, 256, 0, stream>>>(tok, emb, xb);
  k_gemm       <<<dim3(16, 256), 256, 0, stream>>>(xb, wb, bias, xproj);
  k_rec        <<<16, 512, 0, stream>>>(xproj, wfrag8, qscale, hcat);
  k_lin        <<<NTOK / 16, 256, 0, stream>>>(hcat, wltb, blin, logit);
  k_crf        <<<BATCH, 64, 0, stream>>>(logit, lab, slen, trans, startt, endt, T2Tg, cm2g, out);
}

// Round 5
// 2040.299 us; speedup vs baseline: 2.3622x; 1.6946x over previous
//
#include <hip/hip_runtime.h>

// ---------------------------------------------------------------------------
// BiLSTM-CRF fused pipeline for MI355X (gfx950)
// B=64, S=512, V=50000, E=300, H=256 (H2=512), T=48
//   k_rec v4: 64 blocks = (dir 2) x (batch-chunk 32 of 2 rows), 512 threads.
//   W_hh i8 in VGPRs (replicated per block). Per step: MFMA -> raw z to LDS ->
//   barrier -> ALL 512 threads do gate math (1 unit-row each) -> h i8 to LDS.
//   Gate math load-balanced; 10 transcendentals/thread/step. No cross-block sync.
// ---------------------------------------------------------------------------

using short8 = __attribute__((ext_vector_type(8))) short;
using f32x4  = __attribute__((ext_vector_type(4))) float;
using i32x4  = __attribute__((ext_vector_type(4))) int;
typedef unsigned int  uint;
typedef unsigned short ushort;
typedef unsigned long long ull;

#define BATCH 64
#define SEQ   512
#define EMB   300
#define KPAD  320
#define HID   256
#define NTAG  48
#define NTOK  (BATCH*SEQ)          // 32768
#define T2STRIDE 60

__device__ __forceinline__ float bf2f(ushort u) { return __uint_as_float(((uint)u) << 16); }
__device__ __forceinline__ ushort f2bf(float f) {
  uint u = __float_as_uint(f);
  return (ushort)((u + 0x7fffu + ((u >> 16) & 1u)) >> 16);   // RNE
}
__device__ __forceinline__ uint pk2(float a, float b) {
  return (uint)f2bf(a) | ((uint)f2bf(b) << 16);
}

// ---------------------------------------------------------------- prep kernels
__global__ void k_prep_wb(const float* __restrict__ wihf, const float* __restrict__ wihb,
                          ushort* __restrict__ wb) {
  int n = blockIdx.x;            // 0..2047
  int k = threadIdx.x;           // 0..319
  float v = 0.f;
  if (k < EMB) v = (n < 1024) ? wihf[n * EMB + k] : wihb[(n - 1024) * EMB + k];
  wb[n * KPAD + k] = f2bf(v);
}

// W_hh -> i8 rows + per-row dequant scale (includes s_h = 1/127)
__global__ void k_prep_qw(const float* __restrict__ whhf, const float* __restrict__ whhb,
                          uint* __restrict__ wq, float* __restrict__ qscale) {
  int bx = blockIdx.x;           // 0..2047
  int dir = bx >> 10, n = bx & 1023;
  int l = threadIdx.x;           // 0..63
  const float* W = (dir ? whhb : whhf) + (size_t)n * 256 + l * 4;
  float w0 = W[0], w1 = W[1], w2 = W[2], w3 = W[3];
  float mx = fmaxf(fmaxf(fabsf(w0), fabsf(w1)), fmaxf(fabsf(w2), fabsf(w3)));
#pragma unroll
  for (int s = 32; s; s >>= 1) mx = fmaxf(mx, __shfl_xor(mx, s));
  mx = fmaxf(mx, 1e-30f);
  float inv = 127.f / mx;
  if (l == 0) qscale[dir * 1024 + n] = mx * (1.f / 16129.f);   // (mx/127)*(1/127)
  int q0 = (int)rintf(w0 * inv), q1 = (int)rintf(w1 * inv);
  int q2 = (int)rintf(w2 * inv), q3 = (int)rintf(w3 * inv);
  uint b = ((uint)q0 & 0xffu) | (((uint)q1 & 0xffu) << 8) |
           (((uint)q2 & 0xffu) << 16) | (((uint)q3 & 0xffu) << 24);
  wq[(size_t)(dir * 1024 + n) * 64 + l] = b;
}

// i8 B-fragments, wave-contiguous gatecols:
// flat = (((dir*8 + w)*8 + tile)*4 + kc)*64 + lane
// gatecol n = w*128 + tile*16 + (lane&15); k0 = kc*64 + (lane>>4)*16
__global__ void k_prep_wfrag8(const uint* __restrict__ wq, uint4* __restrict__ wfrag8) {
  int flat = blockIdx.x * 256 + threadIdx.x;   // < 32768
  int lane = flat & 63;
  int kc   = (flat >> 6) & 3;
  int tile = (flat >> 8) & 7;
  int w    = (flat >> 11) & 7;
  int dir  = flat >> 14;
  int n = w * 128 + tile * 16 + (lane & 15);
  int k0 = kc * 64 + ((lane >> 4) & 3) * 16;
  const uint4* src = (const uint4*)(wq + (size_t)(dir * 1024 + n) * 64 + k0 / 4);
  wfrag8[flat] = *src;
}

__global__ void k_prep_wlt(const float* __restrict__ wlin, ushort* __restrict__ wltb) {
  int idx = blockIdx.x * 256 + threadIdx.x;   // < 32768
  int k = idx >> 6, j = idx & 63;
  wltb[idx] = f2bf((j < NTAG) ? wlin[j * 512 + k] : 0.f);
}

__global__ void k_prep_small(const float* __restrict__ bihf, const float* __restrict__ bhhf,
                             const float* __restrict__ bihb, const float* __restrict__ bhhb,
                             const float* __restrict__ trans,
                             float* __restrict__ bias, float* __restrict__ T2Tg,
                             float* __restrict__ cm2g, float* __restrict__ out) {
  int tid = threadIdx.x;
  if (tid == 0) out[0] = 0.f;
  for (int i = tid; i < 2048; i += 256)
    bias[i] = (i < 1024) ? (bihf[i] + bhhf[i]) : (bihb[i - 1024] + bhhb[i - 1024]);
  if (tid < NTAG) {
    const float L2E = 1.4426950408889634f;
    float cm = -3.0e38f;
    for (int i = 0; i < NTAG; ++i) cm = fmaxf(cm, trans[i * NTAG + tid] * L2E);
    cm2g[tid] = cm;
    for (int i = 0; i < NTAG; ++i)
      T2Tg[tid * T2STRIDE + i] = trans[i * NTAG + tid] * L2E - cm;
  }
}

// ---------------------------------------------------------------- gather
__global__ __launch_bounds__(256) void k_gather(const int* __restrict__ tok,
                                                const float* __restrict__ emb,
                                                ushort* __restrict__ xb) {
  int r = blockIdx.x * 4 + (threadIdx.x >> 6);   // token row, < 32768
  int l = threadIdx.x & 63;
  int t = tok[r];
  const float* e = emb + (size_t)t * EMB;
  ushort* xr = xb + (size_t)r * KPAD;
#pragma unroll
  for (int q = 0; q < 5; ++q) {
    int k = l + q * 64;
    xr[k] = f2bf((k < EMB) ? e[k] : 0.f);
  }
}

// ---------------------------------------------------------------- input-proj GEMM
// xproj layout: [m][dir*1024 + unit*4 + gate]  (gate-interleaved for k_rec)
__global__ __launch_bounds__(256) void k_gemm(const ushort* __restrict__ xb,
                                              const ushort* __restrict__ wb,
                                              const float* __restrict__ bias,
                                              ushort* __restrict__ xproj) {
  __shared__ __align__(16) ushort Asm[128 * 64];
  __shared__ __align__(16) ushort Bsm[128 * 64];
  const int tid = threadIdx.x;
  const int w = tid >> 6, l = tid & 63;
  const int m0 = blockIdx.y * 128, n0 = blockIdx.x * 128;
  const int wr = (w >> 1) * 64, wc = (w & 1) * 64;
  f32x4 acc[4][4] = {};

  for (int kt = 0; kt < 5; ++kt) {
    const int k0 = kt * 64;
    short8 va[4], vb[4];
#pragma unroll
    for (int i = 0; i < 4; ++i) {
      int cid = tid + 256 * i;
      int row = cid >> 3, slot = cid & 7;
      va[i] = *(const short8*)(xb + (size_t)(m0 + row) * KPAD + k0 + slot * 8);
      vb[i] = *(const short8*)(wb + (size_t)(n0 + row) * KPAD + k0 + slot * 8);
    }
    __syncthreads();
#pragma unroll
    for (int i = 0; i < 4; ++i) {
      int cid = tid + 256 * i;
      int row = cid >> 3, slot = cid & 7;
      int sw = (slot ^ (row & 7)) * 8;
      *(short8*)(&Asm[row * 64 + sw]) = va[i];
      *(short8*)(&Bsm[row * 64 + sw]) = vb[i];
    }
    __syncthreads();
#pragma unroll
    for (int kk = 0; kk < 2; ++kk) {
      int ks = (l >> 4) + kk * 4;
      short8 af[4], bfr[4];
#pragma unroll
      for (int mt = 0; mt < 4; ++mt) {
        int row = wr + mt * 16 + (l & 15);
        af[mt] = *(const short8*)(&Asm[row * 64 + ((ks ^ (row & 7)) * 8)]);
      }
#pragma unroll
      for (int nt = 0; nt < 4; ++nt) {
        int row = wc + nt * 16 + (l & 15);
        bfr[nt] = *(const short8*)(&Bsm[row * 64 + ((ks ^ (row & 7)) * 8)]);
      }
#pragma unroll
      for (int mt = 0; mt < 4; ++mt)
#pragma unroll
        for (int nt = 0; nt < 4; ++nt)
          acc[mt][nt] = __builtin_amdgcn_mfma_f32_16x16x32_bf16(af[mt], bfr[nt], acc[mt][nt], 0, 0, 0);
    }
  }
#pragma unroll
  for (int nt = 0; nt < 4; ++nt) {
    int n = n0 + wc + nt * 16 + (l & 15);
    float bv = bias[n];
    int dirn = n >> 10, gn = (n >> 8) & 3, un = n & 255;
    size_t coff = (size_t)dirn * 1024 + un * 4 + gn;
#pragma unroll
    for (int mt = 0; mt < 4; ++mt) {
      int rbase = m0 + wr + mt * 16 + ((l >> 4) * 4);
#pragma unroll
      for (int r = 0; r < 4; ++r)
        xproj[(size_t)(rbase + r) * 2048 + coff] = f2bf(acc[mt][nt][r] + bv);
    }
  }
}

// ---------------------------------------------------------------- recurrent LSTM
// 64 blocks = (dir) x (chunk of 2 batch rows). 8 waves.
// MFMA phase: wave w computes gatecols [w*128, +128) for 2 rows (M=16, 2 used).
// Gate phase: thread tid -> (row = tid>>8, unit = tid&255).
__global__ __launch_bounds__(512, 2) void k_rec(const ushort* __restrict__ xproj,
                                                const uint4* __restrict__ wfrag8,
                                                const float* __restrict__ qscale,
                                                ushort* __restrict__ hcat) {
  const int blk = blockIdx.x;
  const int dir = blk & 1, chunk = blk >> 1;   // chunk 0..31
  const int bb = chunk * 2;
  const int tid = threadIdx.x, w = tid >> 6, l = tid & 63;
  __shared__ __align__(16) char hlds[2][16 * 256];   // [slot][row16][unit256] i8, granule-XOR swizzle
  __shared__ __align__(16) int  zlds[2][1024];       // [row2][gatecol] raw i32 acc

  // W_hh i8 B-frags -> 128 VGPR, once
  i32x4 wfr[8][4];
  {
    const uint4* wp = wfrag8 + (size_t)(dir * 8 + w) * 2048 + l;
#pragma unroll
    for (int tile = 0; tile < 8; ++tile)
#pragma unroll
      for (int kc = 0; kc < 4; ++kc) {
        union { uint4 u; i32x4 v; } cc;
        cc.u = wp[(tile * 4 + kc) * 64];
        wfr[tile][kc] = cc.v;
      }
  }
  // consumer identity
  const int row  = tid >> 8;        // 0..1
  const int unit = tid & 255;
  float qs4[4];
#pragma unroll
  for (int g = 0; g < 4; ++g) qs4[g] = qscale[dir * 1024 + g * 256 + unit];

  // zero h LDS (rows 2-15 must stay zero forever)
  ((uint4*)hlds)[tid] = uint4{0u, 0u, 0u, 0u};
  __syncthreads();

  const int tt0 = dir ? (SEQ - 1) : 0;
  const ptrdiff_t dstep = dir ? -2048 : 2048;
  const ushort* xp = xproj + ((size_t)(bb + row) * SEQ + tt0) * 2048 + dir * 1024 + unit * 4;
  ull xq_cur = *(const ull*)xp;
  float c = 0.f;
  int tt = tt0;

  for (int t = 0; t < SEQ; ++t) {
    // prefetch next step's xproj (one full step of latency hiding)
    ull xq_nxt = 0;
    if (t + 1 < SEQ) xq_nxt = *(const ull*)(xp + dstep);

    if (t > 0) {
      const char* hs = hlds[(t - 1) & 1];
      const int r16 = l & 15;
      i32x4 a[4];
#pragma unroll
      for (int kc = 0; kc < 4; ++kc) {
        int gr = kc * 4 + (l >> 4);
        a[kc] = *(const i32x4*)(hs + r16 * 256 + ((gr ^ r16) & 15) * 16);
      }
      i32x4 acc[8] = {};
#pragma unroll
      for (int tile = 0; tile < 8; ++tile)
#pragma unroll
        for (int kc = 0; kc < 4; ++kc)
          acc[tile] = __builtin_amdgcn_mfma_i32_16x16x64_i8(a[kc], wfr[tile][kc], acc[tile], 0, 0, 0);
      if (l < 16) {
#pragma unroll
        for (int tile = 0; tile < 8; ++tile) {
          const int col = w * 128 + tile * 16 + l;
          zlds[0][col] = acc[tile][0];
          zlds[1][col] = acc[tile][1];
        }
      }
    }
    __syncthreads();   // z ready

    // --- gate phase: every thread owns (row, unit)
    float zf[4];
#pragma unroll
    for (int g = 0; g < 4; ++g) {
      float zi = (t > 0) ? (float)zlds[row][g * 256 + unit] * qs4[g] : 0.f;
      zf[g] = zi + bf2f((ushort)(xq_cur >> (16 * g)));
    }
    float ig = 1.f / (1.f + __expf(-zf[0]));
    float fg = 1.f / (1.f + __expf(-zf[1]));
    float gg = 2.f / (1.f + __expf(-2.f * zf[2])) - 1.f;
    float og = 1.f / (1.f + __expf(-zf[3]));
    c = fg * c + ig * gg;
    float hv = og * (2.f / (1.f + __expf(-2.f * c)) - 1.f);
    hcat[((size_t)(bb + row) * SEQ + tt) * 512 + dir * 256 + unit] = f2bf(hv);

    // quantize + 4-lane byte pack + swizzled LDS write
    int hq = (int)rintf(hv * 127.f);
    uint v  = (uint)hq & 0xffu;
    uint x1 = __shfl_xor(v, 1);
    uint v2 = __builtin_amdgcn_perm(x1, v, (l & 1) ? 0x00000004u : 0x00000400u);
    uint x2 = __shfl_xor(v2, 2);
    uint v4 = __builtin_amdgcn_perm(x2, v2, (l & 2) ? 0x01000504u : 0x05040100u);
    if (!(l & 3)) {
      const int u0 = unit & ~3;
      *(uint*)(&hlds[t & 1][row * 256 + (((u0 >> 4) ^ row) & 15) * 16 + (u0 & 15)]) = v4;
    }
    __syncthreads();   // h(t) visible, z consumed

    xq_cur = xq_nxt;
    xp += dstep;
    tt += dir ? -1 : 1;
  }
}

// ---------------------------------------------------------------- output linear
__global__ __launch_bounds__(256) void k_lin(const ushort* __restrict__ hcat,
                                             const ushort* __restrict__ wltb,
                                             const float* __restrict__ blin,
                                             float* __restrict__ logits) {
  __shared__ __align__(16) ushort wsm[512 * 64];
  const int tid = threadIdx.x;
#pragma unroll
  for (int i = 0; i < 16; ++i)
    ((short8*)wsm)[tid + 256 * i] = ((const short8*)wltb)[tid + 256 * i];
  __syncthreads();
  const int w = tid >> 6, l = tid & 63;
  float blv = (l < NTAG) ? blin[l] : 0.f;
  for (int q = 0; q < 4; ++q) {
    size_t m = (size_t)blockIdx.x * 16 + w * 4 + q;
    const ushort* hp = hcat + m * 512;
    float acc = blv;
#pragma unroll 2
    for (int k8 = 0; k8 < 64; ++k8) {
      short8 hv = *(const short8*)(hp + k8 * 8);
#pragma unroll
      for (int kk = 0; kk < 8; ++kk)
        acc += bf2f((ushort)hv[kk]) * bf2f(wsm[(k8 * 8 + kk) * 64 + l]);
    }
    if (l < NTAG) logits[m * NTAG + l] = acc;
  }
}

// ---------------------------------------------------------------- CRF
__global__ __launch_bounds__(64) void k_crf(const float* __restrict__ logits,
                                            const int* __restrict__ labels,
                                            const int* __restrict__ slen,
                                            const float* __restrict__ trans,
                                            const float* __restrict__ startt,
                                            const float* __restrict__ endt,
                                            const float* __restrict__ T2Tg,
                                            const float* __restrict__ cm2g,
                                            float* __restrict__ out) {
  __shared__ float Ttab[NTAG * NTAG];
  __shared__ __align__(16) float T2T[NTAG * T2STRIDE];
  __shared__ __align__(16) float As[64];
  __shared__ float cm2[NTAG];
  const int b = blockIdx.x, l = threadIdx.x;
  for (int i = l; i < NTAG * NTAG; i += 64) Ttab[i] = trans[i];
  for (int i = l; i < NTAG * T2STRIDE; i += 64) T2T[i] = T2Tg[i];
  if (l < NTAG) cm2[l] = cm2g[l];
  __syncthreads();
  const float L2E = 1.4426950408889634f;
  const float LN2 = 0.6931471805599453f;
  int len = slen[b]; len = (len < 1) ? 1 : (len > SEQ ? SEQ : len);
  float A = -3.0e38f;
  float score = 0.f;
  int prevtag = 0, lasttag = 0;
  float myend = (l < NTAG) ? endt[l] : 0.f;
  float cmv   = (l < NTAG) ? cm2[l] : 0.f;

  for (int t = 0; t < SEQ; ++t) {
    const float* lg = logits + ((size_t)b * SEQ + t) * NTAG;
    float lv = (l < NTAG) ? lg[l] : -3.0e38f;
    float mx = lv;
#pragma unroll
    for (int s = 32; s; s >>= 1) mx = fmaxf(mx, __shfl_xor(mx, s));
    float e = (l < NTAG) ? exp2f((lv - mx) * L2E) : 0.f;
    float ssum = e;
#pragma unroll
    for (int s = 32; s; s >>= 1) ssum += __shfl_xor(ssum, s);
    float p = e / ssum;
    int tag = labels[(size_t)b * SEQ + t];
    float ptag = __shfl(p, tag);
    if (t == 0) {
      A = (l < NTAG) ? (startt[l] + p) * L2E : -3.0e38f;
      score = startt[tag] + ptag;
      prevtag = tag; lasttag = tag;
    } else if (t < len) {
      float amax = (l < NTAG) ? A : -3.0e38f;
#pragma unroll
      for (int s = 32; s; s >>= 1) amax = fmaxf(amax, __shfl_xor(amax, s));
      As[l] = A - amax;
      __syncthreads();
      if (l < NTAG) {
        float acc2 = 0.f;
#pragma unroll 3
        for (int ic = 0; ic < 12; ++ic) {
          float4 av = *(const float4*)&As[ic * 4];
          float4 tv = *(const float4*)&T2T[l * T2STRIDE + ic * 4];
          acc2 += exp2f(av.x + tv.x);
          acc2 += exp2f(av.y + tv.y);
          acc2 += exp2f(av.z + tv.z);
          acc2 += exp2f(av.w + tv.w);
        }
        A = amax + cmv + log2f(acc2) + p * L2E;
      }
      __syncthreads();
      score += Ttab[prevtag * NTAG + tag] + ptag;
      prevtag = tag; lasttag = tag;
    }
  }
  score += endt[lasttag];
  float v = (l < NTAG) ? (A + myend * L2E) : -3.0e38f;
  float M = v;
#pragma unroll
  for (int s = 32; s; s >>= 1) M = fmaxf(M, __shfl_xor(M, s));
  float sz = (l < NTAG) ? exp2f(v - M) : 0.f;
#pragma unroll
  for (int s = 32; s; s >>= 1) sz += __shfl_xor(sz, s);
  float logz = (M + log2f(sz)) * LN2;
  if (l == 0) atomicAdd(out, logz - score);
}

// ---------------------------------------------------------------- launch
extern "C" void kernel_launch(void* const* d_in, const int* in_sizes, int n_in,
                              void* d_out, int out_size, void* d_ws, size_t ws_size,
                              hipStream_t stream) {
  const int*   tok    = (const int*)d_in[0];
  const int*   slen   = (const int*)d_in[1];
  const int*   lab    = (const int*)d_in[2];
  const float* emb    = (const float*)d_in[3];
  const float* wihf   = (const float*)d_in[4];
  const float* whhf   = (const float*)d_in[5];
  const float* bihf   = (const float*)d_in[6];
  const float* bhhf   = (const float*)d_in[7];
  const float* wihb   = (const float*)d_in[8];
  const float* whhb   = (const float*)d_in[9];
  const float* bihb   = (const float*)d_in[10];
  const float* bhhb   = (const float*)d_in[11];
  const float* wlin   = (const float*)d_in[12];
  const float* blin   = (const float*)d_in[13];
  const float* trans  = (const float*)d_in[14];
  const float* startt = (const float*)d_in[15];
  const float* endt   = (const float*)d_in[16];
  float* out = (float*)d_out;

  char* p = (char*)d_ws;
  ushort* xproj  = (ushort*)p; p += (size_t)NTOK * 2048 * 2;     // 134 MB
  ushort* xb     = (ushort*)p; p += (size_t)NTOK * KPAD * 2;     // 21 MB
  ushort* wb     = (ushort*)p; p += (size_t)2048 * KPAD * 2;     // 1.3 MB
  ushort* hcat   = (ushort*)p; p += (size_t)NTOK * 512 * 2;      // 33.5 MB
  float*  logit  = (float*)p;  p += (size_t)NTOK * NTAG * 4;     // 6.3 MB
  ushort* wltb   = (ushort*)p; p += (size_t)32768 * 2;           // 64 KB
  float*  bias   = (float*)p;  p += 2048 * 4;
  float*  T2Tg   = (float*)p;  p += (size_t)NTAG * T2STRIDE * 4;
  float*  cm2g   = (float*)p;  p += 256;
  uint*   wq     = (uint*)p;   p += (size_t)2048 * 64 * 4;       // 512 KB i8 W_hh rows
  uint4*  wfrag8 = (uint4*)p;  p += (size_t)32768 * 16;          // 512 KB i8 B-frags
  float*  qscale = (float*)p;  p += 2048 * 4;                    // 8 KB

  k_prep_wb    <<<2048, 320, 0, stream>>>(wihf, wihb, wb);
  k_prep_qw    <<<2048, 64, 0, stream>>>(whhf, whhb, wq, qscale);
  k_prep_wfrag8<<<128, 256, 0, stream>>>(wq, wfrag8);
  k_prep_wlt   <<<128, 256, 0, stream>>>(wlin, wltb);
  k_prep_small <<<1, 256, 0, stream>>>(bihf, bhhf, bihb, bhhb, trans, bias, T2Tg, cm2g, out);
  k_gather     <<<NTOK / 4, 256, 0, stream>>>(tok, emb, xb);
  k_gemm       <<<dim3(16, 256), 256, 0, stream>>>(xb, wb, bias, xproj);
  k_rec        <<<64, 512, 0, stream>>>(xproj, wfrag8, qscale, hcat);
  k_lin        <<<NTOK / 16, 256, 0, stream>>>(hcat, wltb, blin, logit);
  k_crf        <<<BATCH, 64, 0, stream>>>(logit, lab, slen, trans, startt, endt, T2Tg, cm2g, out);
}

// Round 6
// 1590.295 us; speedup vs baseline: 3.0307x; 1.2830x over previous
//
#include <hip/hip_runtime.h>

// ---------------------------------------------------------------------------
// BiLSTM-CRF fused pipeline for MI355X (gfx950)
// B=64, S=512, V=50000, E=300, H=256 (H2=512), T=48
//   k_rec v4 (unchanged): 64 blocks, W_hh i8 in VGPRs, load-balanced gates.
//   k_lin v2: logits + FUSED softmax -> p (f32) and pexp = exp(p) (f32).
//   k_score:  parallel CRF numerator (one wave per chain).
//   k_alpha:  sequential CRF denominator in LINEAR domain: 48-FMA matvec per
//             step, exact power-of-2 renorm (exponent extraction), no
//             transcendentals in the loop.
// ---------------------------------------------------------------------------

using short8 = __attribute__((ext_vector_type(8))) short;
using f32x4  = __attribute__((ext_vector_type(4))) float;
using i32x4  = __attribute__((ext_vector_type(4))) int;
typedef unsigned int  uint;
typedef unsigned short ushort;
typedef unsigned long long ull;

#define BATCH 64
#define SEQ   512
#define EMB   300
#define KPAD  320
#define HID   256
#define NTAG  48
#define NTOK  (BATCH*SEQ)          // 32768

__device__ __forceinline__ float bf2f(ushort u) { return __uint_as_float(((uint)u) << 16); }
__device__ __forceinline__ ushort f2bf(float f) {
  uint u = __float_as_uint(f);
  return (ushort)((u + 0x7fffu + ((u >> 16) & 1u)) >> 16);   // RNE
}
__device__ __forceinline__ uint pk2(float a, float b) {
  return (uint)f2bf(a) | ((uint)f2bf(b) << 16);
}

// ---------------------------------------------------------------- prep kernels
__global__ void k_prep_wb(const float* __restrict__ wihf, const float* __restrict__ wihb,
                          ushort* __restrict__ wb) {
  int n = blockIdx.x;            // 0..2047
  int k = threadIdx.x;           // 0..319
  float v = 0.f;
  if (k < EMB) v = (n < 1024) ? wihf[n * EMB + k] : wihb[(n - 1024) * EMB + k];
  wb[n * KPAD + k] = f2bf(v);
}

// W_hh -> i8 rows + per-row dequant scale (includes s_h = 1/127)
__global__ void k_prep_qw(const float* __restrict__ whhf, const float* __restrict__ whhb,
                          uint* __restrict__ wq, float* __restrict__ qscale) {
  int bx = blockIdx.x;           // 0..2047
  int dir = bx >> 10, n = bx & 1023;
  int l = threadIdx.x;           // 0..63
  const float* W = (dir ? whhb : whhf) + (size_t)n * 256 + l * 4;
  float w0 = W[0], w1 = W[1], w2 = W[2], w3 = W[3];
  float mx = fmaxf(fmaxf(fabsf(w0), fabsf(w1)), fmaxf(fabsf(w2), fabsf(w3)));
#pragma unroll
  for (int s = 32; s; s >>= 1) mx = fmaxf(mx, __shfl_xor(mx, s));
  mx = fmaxf(mx, 1e-30f);
  float inv = 127.f / mx;
  if (l == 0) qscale[dir * 1024 + n] = mx * (1.f / 16129.f);   // (mx/127)*(1/127)
  int q0 = (int)rintf(w0 * inv), q1 = (int)rintf(w1 * inv);
  int q2 = (int)rintf(w2 * inv), q3 = (int)rintf(w3 * inv);
  uint b = ((uint)q0 & 0xffu) | (((uint)q1 & 0xffu) << 8) |
           (((uint)q2 & 0xffu) << 16) | (((uint)q3 & 0xffu) << 24);
  wq[(size_t)(dir * 1024 + n) * 64 + l] = b;
}

// i8 B-fragments, wave-contiguous gatecols
__global__ void k_prep_wfrag8(const uint* __restrict__ wq, uint4* __restrict__ wfrag8) {
  int flat = blockIdx.x * 256 + threadIdx.x;   // < 32768
  int lane = flat & 63;
  int kc   = (flat >> 6) & 3;
  int tile = (flat >> 8) & 7;
  int w    = (flat >> 11) & 7;
  int dir  = flat >> 14;
  int n = w * 128 + tile * 16 + (lane & 15);
  int k0 = kc * 64 + ((lane >> 4) & 3) * 16;
  const uint4* src = (const uint4*)(wq + (size_t)(dir * 1024 + n) * 64 + k0 / 4);
  wfrag8[flat] = *src;
}

__global__ void k_prep_wlt(const float* __restrict__ wlin, ushort* __restrict__ wltb) {
  int idx = blockIdx.x * 256 + threadIdx.x;   // < 32768
  int k = idx >> 6, j = idx & 63;
  wltb[idx] = f2bf((j < NTAG) ? wlin[j * 512 + k] : 0.f);
}

// bias fold + out init + E2T[j][i] = 2^(T[i][j]*log2e)  (column-major for k_alpha)
__global__ void k_prep_small(const float* __restrict__ bihf, const float* __restrict__ bhhf,
                             const float* __restrict__ bihb, const float* __restrict__ bhhb,
                             const float* __restrict__ trans,
                             float* __restrict__ bias, float* __restrict__ e2t,
                             float* __restrict__ out) {
  int tid = threadIdx.x;
  if (tid == 0) out[0] = 0.f;
  for (int i = tid; i < 2048; i += 256)
    bias[i] = (i < 1024) ? (bihf[i] + bhhf[i]) : (bihb[i - 1024] + bhhb[i - 1024]);
  const float L2E = 1.4426950408889634f;
  for (int idx = tid; idx < NTAG * NTAG; idx += 256) {
    int j = idx / NTAG, i = idx - j * NTAG;
    e2t[j * NTAG + i] = exp2f(trans[i * NTAG + j] * L2E);
  }
}

// ---------------------------------------------------------------- gather
__global__ __launch_bounds__(256) void k_gather(const int* __restrict__ tok,
                                                const float* __restrict__ emb,
                                                ushort* __restrict__ xb) {
  int r = blockIdx.x * 4 + (threadIdx.x >> 6);   // token row, < 32768
  int l = threadIdx.x & 63;
  int t = tok[r];
  const float* e = emb + (size_t)t * EMB;
  ushort* xr = xb + (size_t)r * KPAD;
#pragma unroll
  for (int q = 0; q < 5; ++q) {
    int k = l + q * 64;
    xr[k] = f2bf((k < EMB) ? e[k] : 0.f);
  }
}

// ---------------------------------------------------------------- input-proj GEMM
// xproj layout: [m][dir*1024 + unit*4 + gate]  (gate-interleaved for k_rec)
__global__ __launch_bounds__(256) void k_gemm(const ushort* __restrict__ xb,
                                              const ushort* __restrict__ wb,
                                              const float* __restrict__ bias,
                                              ushort* __restrict__ xproj) {
  __shared__ __align__(16) ushort Asm[128 * 64];
  __shared__ __align__(16) ushort Bsm[128 * 64];
  const int tid = threadIdx.x;
  const int w = tid >> 6, l = tid & 63;
  const int m0 = blockIdx.y * 128, n0 = blockIdx.x * 128;
  const int wr = (w >> 1) * 64, wc = (w & 1) * 64;
  f32x4 acc[4][4] = {};

  for (int kt = 0; kt < 5; ++kt) {
    const int k0 = kt * 64;
    short8 va[4], vb[4];
#pragma unroll
    for (int i = 0; i < 4; ++i) {
      int cid = tid + 256 * i;
      int row = cid >> 3, slot = cid & 7;
      va[i] = *(const short8*)(xb + (size_t)(m0 + row) * KPAD + k0 + slot * 8);
      vb[i] = *(const short8*)(wb + (size_t)(n0 + row) * KPAD + k0 + slot * 8);
    }
    __syncthreads();
#pragma unroll
    for (int i = 0; i < 4; ++i) {
      int cid = tid + 256 * i;
      int row = cid >> 3, slot = cid & 7;
      int sw = (slot ^ (row & 7)) * 8;
      *(short8*)(&Asm[row * 64 + sw]) = va[i];
      *(short8*)(&Bsm[row * 64 + sw]) = vb[i];
    }
    __syncthreads();
#pragma unroll
    for (int kk = 0; kk < 2; ++kk) {
      int ks = (l >> 4) + kk * 4;
      short8 af[4], bfr[4];
#pragma unroll
      for (int mt = 0; mt < 4; ++mt) {
        int row = wr + mt * 16 + (l & 15);
        af[mt] = *(const short8*)(&Asm[row * 64 + ((ks ^ (row & 7)) * 8)]);
      }
#pragma unroll
      for (int nt = 0; nt < 4; ++nt) {
        int row = wc + nt * 16 + (l & 15);
        bfr[nt] = *(const short8*)(&Bsm[row * 64 + ((ks ^ (row & 7)) * 8)]);
      }
#pragma unroll
      for (int mt = 0; mt < 4; ++mt)
#pragma unroll
        for (int nt = 0; nt < 4; ++nt)
          acc[mt][nt] = __builtin_amdgcn_mfma_f32_16x16x32_bf16(af[mt], bfr[nt], acc[mt][nt], 0, 0, 0);
    }
  }
#pragma unroll
  for (int nt = 0; nt < 4; ++nt) {
    int n = n0 + wc + nt * 16 + (l & 15);
    float bv = bias[n];
    int dirn = n >> 10, gn = (n >> 8) & 3, un = n & 255;
    size_t coff = (size_t)dirn * 1024 + un * 4 + gn;
#pragma unroll
    for (int mt = 0; mt < 4; ++mt) {
      int rbase = m0 + wr + mt * 16 + ((l >> 4) * 4);
#pragma unroll
      for (int r = 0; r < 4; ++r)
        xproj[(size_t)(rbase + r) * 2048 + coff] = f2bf(acc[mt][nt][r] + bv);
    }
  }
}

// ---------------------------------------------------------------- recurrent LSTM
__global__ __launch_bounds__(512, 2) void k_rec(const ushort* __restrict__ xproj,
                                                const uint4* __restrict__ wfrag8,
                                                const float* __restrict__ qscale,
                                                ushort* __restrict__ hcat) {
  const int blk = blockIdx.x;
  const int dir = blk & 1, chunk = blk >> 1;   // chunk 0..31
  const int bb = chunk * 2;
  const int tid = threadIdx.x, w = tid >> 6, l = tid & 63;
  __shared__ __align__(16) char hlds[2][16 * 256];
  __shared__ __align__(16) int  zlds[2][1024];

  i32x4 wfr[8][4];
  {
    const uint4* wp = wfrag8 + (size_t)(dir * 8 + w) * 2048 + l;
#pragma unroll
    for (int tile = 0; tile < 8; ++tile)
#pragma unroll
      for (int kc = 0; kc < 4; ++kc) {
        union { uint4 u; i32x4 v; } cc;
        cc.u = wp[(tile * 4 + kc) * 64];
        wfr[tile][kc] = cc.v;
      }
  }
  const int row  = tid >> 8;        // 0..1
  const int unit = tid & 255;
  float qs4[4];
#pragma unroll
  for (int g = 0; g < 4; ++g) qs4[g] = qscale[dir * 1024 + g * 256 + unit];

  ((uint4*)hlds)[tid] = uint4{0u, 0u, 0u, 0u};
  __syncthreads();

  const int tt0 = dir ? (SEQ - 1) : 0;
  const ptrdiff_t dstep = dir ? -2048 : 2048;
  const ushort* xp = xproj + ((size_t)(bb + row) * SEQ + tt0) * 2048 + dir * 1024 + unit * 4;
  ull xq_cur = *(const ull*)xp;
  float c = 0.f;
  int tt = tt0;

  for (int t = 0; t < SEQ; ++t) {
    ull xq_nxt = 0;
    if (t + 1 < SEQ) xq_nxt = *(const ull*)(xp + dstep);

    if (t > 0) {
      const char* hs = hlds[(t - 1) & 1];
      const int r16 = l & 15;
      i32x4 a[4];
#pragma unroll
      for (int kc = 0; kc < 4; ++kc) {
        int gr = kc * 4 + (l >> 4);
        a[kc] = *(const i32x4*)(hs + r16 * 256 + ((gr ^ r16) & 15) * 16);
      }
      i32x4 acc[8] = {};
#pragma unroll
      for (int tile = 0; tile < 8; ++tile)
#pragma unroll
        for (int kc = 0; kc < 4; ++kc)
          acc[tile] = __builtin_amdgcn_mfma_i32_16x16x64_i8(a[kc], wfr[tile][kc], acc[tile], 0, 0, 0);
      if (l < 16) {
#pragma unroll
        for (int tile = 0; tile < 8; ++tile) {
          const int col = w * 128 + tile * 16 + l;
          zlds[0][col] = acc[tile][0];
          zlds[1][col] = acc[tile][1];
        }
      }
    }
    __syncthreads();   // z ready

    float zf[4];
#pragma unroll
    for (int g = 0; g < 4; ++g) {
      float zi = (t > 0) ? (float)zlds[row][g * 256 + unit] * qs4[g] : 0.f;
      zf[g] = zi + bf2f((ushort)(xq_cur >> (16 * g)));
    }
    float ig = 1.f / (1.f + __expf(-zf[0]));
    float fg = 1.f / (1.f + __expf(-zf[1]));
    float gg = 2.f / (1.f + __expf(-2.f * zf[2])) - 1.f;
    float og = 1.f / (1.f + __expf(-zf[3]));
    c = fg * c + ig * gg;
    float hv = og * (2.f / (1.f + __expf(-2.f * c)) - 1.f);
    hcat[((size_t)(bb + row) * SEQ + tt) * 512 + dir * 256 + unit] = f2bf(hv);

    int hq = (int)rintf(hv * 127.f);
    uint v  = (uint)hq & 0xffu;
    uint x1 = __shfl_xor(v, 1);
    uint v2 = __builtin_amdgcn_perm(x1, v, (l & 1) ? 0x00000004u : 0x00000400u);
    uint x2 = __shfl_xor(v2, 2);
    uint v4 = __builtin_amdgcn_perm(x2, v2, (l & 2) ? 0x01000504u : 0x05040100u);
    if (!(l & 3)) {
      const int u0 = unit & ~3;
      *(uint*)(&hlds[t & 1][row * 256 + (((u0 >> 4) ^ row) & 15) * 16 + (u0 & 15)]) = v4;
    }
    __syncthreads();   // h(t) visible, z consumed

    xq_cur = xq_nxt;
    xp += dstep;
    tt += dir ? -1 : 1;
  }
}

// ---------------------------------------------------------------- output linear + softmax
// stores p[m][48] (f32 softmax probs) and pexp[m][48] = exp(p)
__global__ __launch_bounds__(256) void k_lin(const ushort* __restrict__ hcat,
                                             const ushort* __restrict__ wltb,
                                             const float* __restrict__ blin,
                                             float* __restrict__ p,
                                             float* __restrict__ pexp) {
  __shared__ __align__(16) ushort wsm[512 * 64];
  const int tid = threadIdx.x;
#pragma unroll
  for (int i = 0; i < 16; ++i)
    ((short8*)wsm)[tid + 256 * i] = ((const short8*)wltb)[tid + 256 * i];
  __syncthreads();
  const int w = tid >> 6, l = tid & 63;
  const float L2E = 1.4426950408889634f;
  float blv = (l < NTAG) ? blin[l] : 0.f;
  for (int q = 0; q < 4; ++q) {
    size_t m = (size_t)blockIdx.x * 16 + w * 4 + q;
    const ushort* hp = hcat + m * 512;
    float acc = blv;
#pragma unroll 2
    for (int k8 = 0; k8 < 64; ++k8) {
      short8 hv = *(const short8*)(hp + k8 * 8);
#pragma unroll
      for (int kk = 0; kk < 8; ++kk)
        acc += bf2f((ushort)hv[kk]) * bf2f(wsm[(k8 * 8 + kk) * 64 + l]);
    }
    // fused softmax across lanes (tags)
    float mx = (l < NTAG) ? acc : -3.0e38f;
#pragma unroll
    for (int s = 32; s; s >>= 1) mx = fmaxf(mx, __shfl_xor(mx, s));
    float e = (l < NTAG) ? exp2f((acc - mx) * L2E) : 0.f;
    float ssum = e;
#pragma unroll
    for (int s = 32; s; s >>= 1) ssum += __shfl_xor(ssum, s);
    float pv = e / ssum;
    if (l < NTAG) {
      p[m * NTAG + l] = pv;
      pexp[m * NTAG + l] = exp2f(pv * L2E);
    }
  }
}

// ---------------------------------------------------------------- CRF numerator (parallel)
__global__ __launch_bounds__(64) void k_score(const float* __restrict__ p,
                                              const int* __restrict__ labels,
                                              const int* __restrict__ slen,
                                              const float* __restrict__ trans,
                                              const float* __restrict__ startt,
                                              const float* __restrict__ endt,
                                              float* __restrict__ out) {
  const int b = blockIdx.x, l = threadIdx.x;
  int len = slen[b]; len = (len < 1) ? 1 : (len > SEQ ? SEQ : len);
  const int* tg = labels + (size_t)b * SEQ;
  float part = 0.f;
  for (int t = l; t < len; t += 64) {
    int tag = tg[t];
    part += p[((size_t)b * SEQ + t) * NTAG + tag];
    if (t >= 1)       part += trans[tg[t - 1] * NTAG + tag];
    if (t == 0)       part += startt[tag];
    if (t == len - 1) part += endt[tag];
  }
#pragma unroll
  for (int s = 32; s; s >>= 1) part += __shfl_xor(part, s);
  if (l == 0) atomicAdd(out, -part);
}

// ---------------------------------------------------------------- CRF forward (sequential, linear domain)
__global__ __launch_bounds__(64) void k_alpha(const float* __restrict__ p,
                                              const float* __restrict__ pexp,
                                              const float* __restrict__ e2t,
                                              const int* __restrict__ slen,
                                              const float* __restrict__ startt,
                                              const float* __restrict__ endt,
                                              float* __restrict__ out) {
  const int b = blockIdx.x, j = threadIdx.x;
  const float L2E = 1.4426950408889634f, LN2 = 0.6931471805599453f;
  int len = slen[b]; len = (len < 1) ? 1 : (len > SEQ ? SEQ : len);
  // E2 column of tag j: e2[i] = 2^(T[i][j]*L2E)
  float e2[NTAG];
  if (j < NTAG) {
    const float4* er = (const float4*)(e2t + j * NTAG);
#pragma unroll
    for (int q = 0; q < 12; ++q) {
      float4 v = er[q];
      e2[q * 4] = v.x; e2[q * 4 + 1] = v.y; e2[q * 4 + 2] = v.z; e2[q * 4 + 3] = v.w;
    }
  } else {
#pragma unroll
    for (int q = 0; q < NTAG; ++q) e2[q] = 0.f;
  }
  float A0 = (j < NTAG) ? (startt[j] + p[((size_t)b * SEQ) * NTAG + j]) * L2E : -3.0e38f;
  float m = A0;
#pragma unroll
  for (int s = 32; s; s >>= 1) m = fmaxf(m, __shfl_xor(m, s));
  float a = (j < NTAG) ? exp2f(A0 - m) : 0.f;
  float acc = m;
  const float* pe = pexp + ((size_t)b * SEQ) * NTAG + j;
  float pe_cur = (j < NTAG && len > 1) ? pe[NTAG] : 0.f;

  for (int t = 1; t < len; ++t) {
    float pe_next = (j < NTAG && t + 1 < len) ? pe[(size_t)(t + 1) * NTAG] : 0.f;
    float c0 = 0.f, c1 = 0.f, c2 = 0.f, c3 = 0.f;
#pragma unroll
    for (int i = 0; i < NTAG; i += 4) {
      c0 = fmaf(__shfl(a, i),     e2[i],     c0);
      c1 = fmaf(__shfl(a, i + 1), e2[i + 1], c1);
      c2 = fmaf(__shfl(a, i + 2), e2[i + 2], c2);
      c3 = fmaf(__shfl(a, i + 3), e2[i + 3], c3);
    }
    float na = (j < NTAG) ? ((c0 + c1) + (c2 + c3)) * pe_cur : 0.f;
    float s = na;
#pragma unroll
    for (int q = 32; q; q >>= 1) s += __shfl_xor(s, q);
    int es = (int)(__float_as_uint(s) >> 23) - 127;        // floor(log2 s), s>0 normal
    float scale = __uint_as_float((uint)(127 - es) << 23); // exact 2^-es
    a = na * scale;
    acc += (float)es;
    pe_cur = pe_next;
  }
  float v = (j < NTAG) ? a * exp2f(endt[j] * L2E) : 0.f;
  float s = v;
#pragma unroll
  for (int q = 32; q; q >>= 1) s += __shfl_xor(s, q);
  if (j == 0) atomicAdd(out, (acc + log2f(s)) * LN2);
}

// ---------------------------------------------------------------- launch
extern "C" void kernel_launch(void* const* d_in, const int* in_sizes, int n_in,
                              void* d_out, int out_size, void* d_ws, size_t ws_size,
                              hipStream_t stream) {
  const int*   tok    = (const int*)d_in[0];
  const int*   slen   = (const int*)d_in[1];
  const int*   lab    = (const int*)d_in[2];
  const float* emb    = (const float*)d_in[3];
  const float* wihf   = (const float*)d_in[4];
  const float* whhf   = (const float*)d_in[5];
  const float* bihf   = (const float*)d_in[6];
  const float* bhhf   = (const float*)d_in[7];
  const float* wihb   = (const float*)d_in[8];
  const float* whhb   = (const float*)d_in[9];
  const float* bihb   = (const float*)d_in[10];
  const float* bhhb   = (const float*)d_in[11];
  const float* wlin   = (const float*)d_in[12];
  const float* blin   = (const float*)d_in[13];
  const float* trans  = (const float*)d_in[14];
  const float* startt = (const float*)d_in[15];
  const float* endt   = (const float*)d_in[16];
  float* out = (float*)d_out;

  char* p = (char*)d_ws;
  ushort* xproj  = (ushort*)p; p += (size_t)NTOK * 2048 * 2;     // 134 MB
  ushort* xb     = (ushort*)p; p += (size_t)NTOK * KPAD * 2;     // 21 MB
  ushort* wb     = (ushort*)p; p += (size_t)2048 * KPAD * 2;     // 1.3 MB
  ushort* hcat   = (ushort*)p; p += (size_t)NTOK * 512 * 2;      // 33.5 MB
  float*  pbuf   = (float*)p;  p += (size_t)NTOK * NTAG * 4;     // 6.3 MB softmax probs
  float*  pexp   = (float*)p;  p += (size_t)NTOK * NTAG * 4;     // 6.3 MB exp(p)
  ushort* wltb   = (ushort*)p; p += (size_t)32768 * 2;           // 64 KB
  float*  bias   = (float*)p;  p += 2048 * 4;
  float*  e2t    = (float*)p;  p += (size_t)NTAG * NTAG * 4;     // 9 KB
  uint*   wq     = (uint*)p;   p += (size_t)2048 * 64 * 4;       // 512 KB
  uint4*  wfrag8 = (uint4*)p;  p += (size_t)32768 * 16;          // 512 KB
  float*  qscale = (float*)p;  p += 2048 * 4;                    // 8 KB

  k_prep_wb    <<<2048, 320, 0, stream>>>(wihf, wihb, wb);
  k_prep_qw    <<<2048, 64, 0, stream>>>(whhf, whhb, wq, qscale);
  k_prep_wfrag8<<<128, 256, 0, stream>>>(wq, wfrag8);
  k_prep_wlt   <<<128, 256, 0, stream>>>(wlin, wltb);
  k_prep_small <<<1, 256, 0, stream>>>(bihf, bhhf, bihb, bhhb, trans, bias, e2t, out);
  k_gather     <<<NTOK / 4, 256, 0, stream>>>(tok, emb, xb);
  k_gemm       <<<dim3(16, 256), 256, 0, stream>>>(xb, wb, bias, xproj);
  k_rec        <<<64, 512, 0, stream>>>(xproj, wfrag8, qscale, hcat);
  k_lin        <<<NTOK / 16, 256, 0, stream>>>(hcat, wltb, blin, pbuf, pexp);
  k_score      <<<BATCH, 64, 0, stream>>>(pbuf, lab, slen, trans, startt, endt, out);
  k_alpha      <<<BATCH, 64, 0, stream>>>(pbuf, pexp, e2t, slen, startt, endt, out);
}

// Round 7
// 1470.640 us; speedup vs baseline: 3.2773x; 1.0814x over previous
//
#include <hip/hip_runtime.h>

// ---------------------------------------------------------------------------
// BiLSTM-CRF fused pipeline for MI355X (gfx950)
// B=64, S=512, V=50000, E=300, H=256 (H2=512), T=48
//   k_rec v4: 64 blocks, W_hh i8 in VGPRs, load-balanced gates (unchanged core).
//   k_gemm: xproj in natural layout (coalesced epilogue).
//   k_lin v3: MFMA GEMM (32768x48x512) + fused softmax -> p (f32).
//   k_score / k_alpha: CRF numerator (parallel) / linear-domain forward scan.
// ---------------------------------------------------------------------------

using short8 = __attribute__((ext_vector_type(8))) short;
using f32x4  = __attribute__((ext_vector_type(4))) float;
using i32x4  = __attribute__((ext_vector_type(4))) int;
typedef unsigned int  uint;
typedef unsigned short ushort;
typedef unsigned long long ull;

#define BATCH 64
#define SEQ   512
#define EMB   300
#define KPAD  320
#define HID   256
#define NTAG  48
#define NTOK  (BATCH*SEQ)          // 32768

__device__ __forceinline__ float bf2f(ushort u) { return __uint_as_float(((uint)u) << 16); }
__device__ __forceinline__ ushort f2bf(float f) {
  uint u = __float_as_uint(f);
  return (ushort)((u + 0x7fffu + ((u >> 16) & 1u)) >> 16);   // RNE
}
__device__ __forceinline__ uint pk2(float a, float b) {
  return (uint)f2bf(a) | ((uint)f2bf(b) << 16);
}

// ---------------------------------------------------------------- prep kernels
__global__ void k_prep_wb(const float* __restrict__ wihf, const float* __restrict__ wihb,
                          ushort* __restrict__ wb) {
  int n = blockIdx.x;            // 0..2047
  int k = threadIdx.x;           // 0..319
  float v = 0.f;
  if (k < EMB) v = (n < 1024) ? wihf[n * EMB + k] : wihb[(n - 1024) * EMB + k];
  wb[n * KPAD + k] = f2bf(v);
}

// W_hh -> i8 rows + per-row dequant scale (includes s_h = 1/127)
__global__ void k_prep_qw(const float* __restrict__ whhf, const float* __restrict__ whhb,
                          uint* __restrict__ wq, float* __restrict__ qscale) {
  int bx = blockIdx.x;           // 0..2047
  int dir = bx >> 10, n = bx & 1023;
  int l = threadIdx.x;           // 0..63
  const float* W = (dir ? whhb : whhf) + (size_t)n * 256 + l * 4;
  float w0 = W[0], w1 = W[1], w2 = W[2], w3 = W[3];
  float mx = fmaxf(fmaxf(fabsf(w0), fabsf(w1)), fmaxf(fabsf(w2), fabsf(w3)));
#pragma unroll
  for (int s = 32; s; s >>= 1) mx = fmaxf(mx, __shfl_xor(mx, s));
  mx = fmaxf(mx, 1e-30f);
  float inv = 127.f / mx;
  if (l == 0) qscale[dir * 1024 + n] = mx * (1.f / 16129.f);   // (mx/127)*(1/127)
  int q0 = (int)rintf(w0 * inv), q1 = (int)rintf(w1 * inv);
  int q2 = (int)rintf(w2 * inv), q3 = (int)rintf(w3 * inv);
  uint b = ((uint)q0 & 0xffu) | (((uint)q1 & 0xffu) << 8) |
           (((uint)q2 & 0xffu) << 16) | (((uint)q3 & 0xffu) << 24);
  wq[(size_t)(dir * 1024 + n) * 64 + l] = b;
}

// i8 B-fragments, wave-contiguous gatecols
__global__ void k_prep_wfrag8(const uint* __restrict__ wq, uint4* __restrict__ wfrag8) {
  int flat = blockIdx.x * 256 + threadIdx.x;   // < 32768
  int lane = flat & 63;
  int kc   = (flat >> 6) & 3;
  int tile = (flat >> 8) & 7;
  int w    = (flat >> 11) & 7;
  int dir  = flat >> 14;
  int n = w * 128 + tile * 16 + (lane & 15);
  int k0 = kc * 64 + ((lane >> 4) & 3) * 16;
  const uint4* src = (const uint4*)(wq + (size_t)(dir * 1024 + n) * 64 + k0 / 4);
  wfrag8[flat] = *src;
}

// W_lin -> bf16 B-fragments for k_lin: [(kk*3+nt)*64+lane] x short8
// tag = nt*16+(lane&15), k = kk*32 + (lane>>4)*8 + j
__global__ void k_prep_wlt(const float* __restrict__ wlin, ushort* __restrict__ wfragL) {
  int idx = blockIdx.x * 256 + threadIdx.x;   // < 24576
  int j    = idx & 7;
  int lane = (idx >> 3) & 63;
  int c    = idx >> 9;              // kk*3+nt, 0..47
  int nt = c % 3, kk = c / 3;
  int tag = nt * 16 + (lane & 15);
  int k   = kk * 32 + (lane >> 4) * 8 + j;
  wfragL[idx] = f2bf(wlin[tag * 512 + k]);
}

// bias fold + out init + E2T[j][i] = 2^(T[i][j]*log2e)  (column-major for k_alpha)
__global__ void k_prep_small(const float* __restrict__ bihf, const float* __restrict__ bhhf,
                             const float* __restrict__ bihb, const float* __restrict__ bhhb,
                             const float* __restrict__ trans,
                             float* __restrict__ bias, float* __restrict__ e2t,
                             float* __restrict__ out) {
  int tid = threadIdx.x;
  if (tid == 0) out[0] = 0.f;
  for (int i = tid; i < 2048; i += 256)
    bias[i] = (i < 1024) ? (bihf[i] + bhhf[i]) : (bihb[i - 1024] + bhhb[i - 1024]);
  const float L2E = 1.4426950408889634f;
  for (int idx = tid; idx < NTAG * NTAG; idx += 256) {
    int j = idx / NTAG, i = idx - j * NTAG;
    e2t[j * NTAG + i] = exp2f(trans[i * NTAG + j] * L2E);
  }
}

// ---------------------------------------------------------------- gather
__global__ __launch_bounds__(256) void k_gather(const int* __restrict__ tok,
                                                const float* __restrict__ emb,
                                                ushort* __restrict__ xb) {
  int r = blockIdx.x * 4 + (threadIdx.x >> 6);   // token row, < 32768
  int l = threadIdx.x & 63;
  int t = tok[r];
  const float* e = emb + (size_t)t * EMB;
  ushort* xr = xb + (size_t)r * KPAD;
#pragma unroll
  for (int q = 0; q < 5; ++q) {
    int k = l + q * 64;
    xr[k] = f2bf((k < EMB) ? e[k] : 0.f);
  }
}

// ---------------------------------------------------------------- input-proj GEMM
// xproj layout: [m][dir*1024 + g*256 + unit]  (natural; coalesced epilogue)
__global__ __launch_bounds__(256) void k_gemm(const ushort* __restrict__ xb,
                                              const ushort* __restrict__ wb,
                                              const float* __restrict__ bias,
                                              ushort* __restrict__ xproj) {
  __shared__ __align__(16) ushort Asm[128 * 64];
  __shared__ __align__(16) ushort Bsm[128 * 64];
  const int tid = threadIdx.x;
  const int w = tid >> 6, l = tid & 63;
  const int m0 = blockIdx.y * 128, n0 = blockIdx.x * 128;
  const int wr = (w >> 1) * 64, wc = (w & 1) * 64;
  f32x4 acc[4][4] = {};

  for (int kt = 0; kt < 5; ++kt) {
    const int k0 = kt * 64;
    short8 va[4], vb[4];
#pragma unroll
    for (int i = 0; i < 4; ++i) {
      int cid = tid + 256 * i;
      int row = cid >> 3, slot = cid & 7;
      va[i] = *(const short8*)(xb + (size_t)(m0 + row) * KPAD + k0 + slot * 8);
      vb[i] = *(const short8*)(wb + (size_t)(n0 + row) * KPAD + k0 + slot * 8);
    }
    __syncthreads();
#pragma unroll
    for (int i = 0; i < 4; ++i) {
      int cid = tid + 256 * i;
      int row = cid >> 3, slot = cid & 7;
      int sw = (slot ^ (row & 7)) * 8;
      *(short8*)(&Asm[row * 64 + sw]) = va[i];
      *(short8*)(&Bsm[row * 64 + sw]) = vb[i];
    }
    __syncthreads();
#pragma unroll
    for (int kk = 0; kk < 2; ++kk) {
      int ks = (l >> 4) + kk * 4;
      short8 af[4], bfr[4];
#pragma unroll
      for (int mt = 0; mt < 4; ++mt) {
        int row = wr + mt * 16 + (l & 15);
        af[mt] = *(const short8*)(&Asm[row * 64 + ((ks ^ (row & 7)) * 8)]);
      }
#pragma unroll
      for (int nt = 0; nt < 4; ++nt) {
        int row = wc + nt * 16 + (l & 15);
        bfr[nt] = *(const short8*)(&Bsm[row * 64 + ((ks ^ (row & 7)) * 8)]);
      }
#pragma unroll
      for (int mt = 0; mt < 4; ++mt)
#pragma unroll
        for (int nt = 0; nt < 4; ++nt)
          acc[mt][nt] = __builtin_amdgcn_mfma_f32_16x16x32_bf16(af[mt], bfr[nt], acc[mt][nt], 0, 0, 0);
    }
  }
#pragma unroll
  for (int nt = 0; nt < 4; ++nt) {
    int n = n0 + wc + nt * 16 + (l & 15);
    float bv = bias[n];
#pragma unroll
    for (int mt = 0; mt < 4; ++mt) {
      int rbase = m0 + wr + mt * 16 + ((l >> 4) * 4);
#pragma unroll
      for (int r = 0; r < 4; ++r)
        xproj[(size_t)(rbase + r) * 2048 + n] = f2bf(acc[mt][nt][r] + bv);
    }
  }
}

// ---------------------------------------------------------------- recurrent LSTM
__global__ __launch_bounds__(512, 2) void k_rec(const ushort* __restrict__ xproj,
                                                const uint4* __restrict__ wfrag8,
                                                const float* __restrict__ qscale,
                                                ushort* __restrict__ hcat) {
  const int blk = blockIdx.x;
  const int dir = blk & 1, chunk = blk >> 1;   // chunk 0..31
  const int bb = chunk * 2;
  const int tid = threadIdx.x, w = tid >> 6, l = tid & 63;
  __shared__ __align__(16) char hlds[2][16 * 256];
  __shared__ __align__(16) int  zlds[2][1024];

  i32x4 wfr[8][4];
  {
    const uint4* wp = wfrag8 + (size_t)(dir * 8 + w) * 2048 + l;
#pragma unroll
    for (int tile = 0; tile < 8; ++tile)
#pragma unroll
      for (int kc = 0; kc < 4; ++kc) {
        union { uint4 u; i32x4 v; } cc;
        cc.u = wp[(tile * 4 + kc) * 64];
        wfr[tile][kc] = cc.v;
      }
  }
  const int row  = tid >> 8;        // 0..1
  const int unit = tid & 255;
  float qs4[4];
#pragma unroll
  for (int g = 0; g < 4; ++g) qs4[g] = qscale[dir * 1024 + g * 256 + unit];

  ((uint4*)hlds)[tid] = uint4{0u, 0u, 0u, 0u};
  __syncthreads();

  const int tt0 = dir ? (SEQ - 1) : 0;
  const ptrdiff_t dstep = dir ? -2048 : 2048;
  const ushort* xp = xproj + ((size_t)(bb + row) * SEQ + tt0) * 2048 + dir * 1024 + unit;
  ushort xs[4];
#pragma unroll
  for (int g = 0; g < 4; ++g) xs[g] = xp[g * 256];
  float c = 0.f;
  int tt = tt0;

  for (int t = 0; t < SEQ; ++t) {
    ushort xn[4] = {0, 0, 0, 0};
    if (t + 1 < SEQ) {
      const ushort* xpn = xp + dstep;
#pragma unroll
      for (int g = 0; g < 4; ++g) xn[g] = xpn[g * 256];
    }

    if (t > 0) {
      const char* hs = hlds[(t - 1) & 1];
      const int r16 = l & 15;
      i32x4 a[4];
#pragma unroll
      for (int kc = 0; kc < 4; ++kc) {
        int gr = kc * 4 + (l >> 4);
        a[kc] = *(const i32x4*)(hs + r16 * 256 + ((gr ^ r16) & 15) * 16);
      }
      i32x4 acc[8] = {};
#pragma unroll
      for (int tile = 0; tile < 8; ++tile)
#pragma unroll
        for (int kc = 0; kc < 4; ++kc)
          acc[tile] = __builtin_amdgcn_mfma_i32_16x16x64_i8(a[kc], wfr[tile][kc], acc[tile], 0, 0, 0);
      if (l < 16) {
#pragma unroll
        for (int tile = 0; tile < 8; ++tile) {
          const int col = w * 128 + tile * 16 + l;
          zlds[0][col] = acc[tile][0];
          zlds[1][col] = acc[tile][1];
        }
      }
    }
    __syncthreads();   // z ready

    float zf[4];
#pragma unroll
    for (int g = 0; g < 4; ++g) {
      float zi = (t > 0) ? (float)zlds[row][g * 256 + unit] * qs4[g] : 0.f;
      zf[g] = zi + bf2f(xs[g]);
    }
    float ig = 1.f / (1.f + __expf(-zf[0]));
    float fg = 1.f / (1.f + __expf(-zf[1]));
    float gg = 2.f / (1.f + __expf(-2.f * zf[2])) - 1.f;
    float og = 1.f / (1.f + __expf(-zf[3]));
    c = fg * c + ig * gg;
    float hv = og * (2.f / (1.f + __expf(-2.f * c)) - 1.f);
    hcat[((size_t)(bb + row) * SEQ + tt) * 512 + dir * 256 + unit] = f2bf(hv);

    int hq = (int)rintf(hv * 127.f);
    uint v  = (uint)hq & 0xffu;
    uint x1 = __shfl_xor(v, 1);
    uint v2 = __builtin_amdgcn_perm(x1, v, (l & 1) ? 0x00000004u : 0x00000400u);
    uint x2 = __shfl_xor(v2, 2);
    uint v4 = __builtin_amdgcn_perm(x2, v2, (l & 2) ? 0x01000504u : 0x05040100u);
    if (!(l & 3)) {
      const int u0 = unit & ~3;
      *(uint*)(&hlds[t & 1][row * 256 + (((u0 >> 4) ^ row) & 15) * 16 + (u0 & 15)]) = v4;
    }
    __syncthreads();   // h(t) visible, z consumed

#pragma unroll
    for (int g = 0; g < 4; ++g) xs[g] = xn[g];
    xp += dstep;
    tt += dir ? -1 : 1;
  }
}

// ---------------------------------------------------------------- output linear (MFMA) + fused softmax
// 256 blocks x 128 rows; wave w owns mtiles {2w, 2w+1}; tags in nt 0..2.
__global__ __launch_bounds__(256) void k_lin(const ushort* __restrict__ hcat,
                                             const ushort* __restrict__ wfragL,
                                             const float* __restrict__ blin,
                                             float* __restrict__ p) {
  __shared__ __align__(16) ushort Asm[128 * 64];
  const int tid = threadIdx.x;
  const int w = tid >> 6, l = tid & 63;
  const size_t m0 = (size_t)blockIdx.x * 128;
  const float L2E = 1.4426950408889634f;
  f32x4 acc[2][3] = {};

  for (int kb = 0; kb < 8; ++kb) {        // BK = 64
    short8 va[4];
#pragma unroll
    for (int i = 0; i < 4; ++i) {
      int cid = tid + 256 * i;
      int row = cid >> 3, slot = cid & 7;
      va[i] = *(const short8*)(hcat + (m0 + row) * 512 + kb * 64 + slot * 8);
    }
    __syncthreads();
#pragma unroll
    for (int i = 0; i < 4; ++i) {
      int cid = tid + 256 * i;
      int row = cid >> 3, slot = cid & 7;
      *(short8*)(&Asm[row * 64 + ((slot ^ (row & 7)) * 8)]) = va[i];
    }
    __syncthreads();
#pragma unroll
    for (int kk = 0; kk < 2; ++kk) {
      int ks = (l >> 4) + kk * 4;
      short8 af[2], bfr[3];
#pragma unroll
      for (int mt = 0; mt < 2; ++mt) {
        int row = (w * 2 + mt) * 16 + (l & 15);
        af[mt] = *(const short8*)(&Asm[row * 64 + ((ks ^ (row & 7)) * 8)]);
      }
#pragma unroll
      for (int nt = 0; nt < 3; ++nt)
        bfr[nt] = *(const short8*)(wfragL + (size_t)(((kb * 2 + kk) * 3 + nt) * 64 + l) * 8);
#pragma unroll
      for (int mt = 0; mt < 2; ++mt)
#pragma unroll
        for (int nt = 0; nt < 3; ++nt)
          acc[mt][nt] = __builtin_amdgcn_mfma_f32_16x16x32_bf16(af[mt], bfr[nt], acc[mt][nt], 0, 0, 0);
    }
  }
  float bl0 = blin[l & 15], bl1 = blin[16 + (l & 15)], bl2 = blin[32 + (l & 15)];
#pragma unroll
  for (int mt = 0; mt < 2; ++mt) {
#pragma unroll
    for (int r = 0; r < 4; ++r) {
      size_t row = m0 + (w * 2 + mt) * 16 + (l >> 4) * 4 + r;
      float v0 = acc[mt][0][r] + bl0;
      float v1 = acc[mt][1][r] + bl1;
      float v2 = acc[mt][2][r] + bl2;
      float mx = fmaxf(fmaxf(v0, v1), v2);
#pragma unroll
      for (int s = 8; s; s >>= 1) mx = fmaxf(mx, __shfl_xor(mx, s));
      float e0 = exp2f((v0 - mx) * L2E);
      float e1 = exp2f((v1 - mx) * L2E);
      float e2 = exp2f((v2 - mx) * L2E);
      float ssum = e0 + e1 + e2;
#pragma unroll
      for (int s = 8; s; s >>= 1) ssum += __shfl_xor(ssum, s);
      float inv = 1.f / ssum;
      p[row * NTAG +      (l & 15)] = e0 * inv;
      p[row * NTAG + 16 + (l & 15)] = e1 * inv;
      p[row * NTAG + 32 + (l & 15)] = e2 * inv;
    }
  }
}

// ---------------------------------------------------------------- CRF numerator (parallel)
__global__ __launch_bounds__(64) void k_score(const float* __restrict__ p,
                                              const int* __restrict__ labels,
                                              const int* __restrict__ slen,
                                              const float* __restrict__ trans,
                                              const float* __restrict__ startt,
                                              const float* __restrict__ endt,
                                              float* __restrict__ out) {
  const int b = blockIdx.x, l = threadIdx.x;
  int len = slen[b]; len = (len < 1) ? 1 : (len > SEQ ? SEQ : len);
  const int* tg = labels + (size_t)b * SEQ;
  float part = 0.f;
  for (int t = l; t < len; t += 64) {
    int tag = tg[t];
    part += p[((size_t)b * SEQ + t) * NTAG + tag];
    if (t >= 1)       part += trans[tg[t - 1] * NTAG + tag];
    if (t == 0)       part += startt[tag];
    if (t == len - 1) part += endt[tag];
  }
#pragma unroll
  for (int s = 32; s; s >>= 1) part += __shfl_xor(part, s);
  if (l == 0) atomicAdd(out, -part);
}

// ---------------------------------------------------------------- CRF forward (sequential, linear domain)
__global__ __launch_bounds__(64) void k_alpha(const float* __restrict__ p,
                                              const float* __restrict__ e2t,
                                              const int* __restrict__ slen,
                                              const float* __restrict__ startt,
                                              const float* __restrict__ endt,
                                              float* __restrict__ out) {
  const int b = blockIdx.x, j = threadIdx.x;
  const float L2E = 1.4426950408889634f, LN2 = 0.6931471805599453f;
  int len = slen[b]; len = (len < 1) ? 1 : (len > SEQ ? SEQ : len);
  float e2[NTAG];
  if (j < NTAG) {
    const float4* er = (const float4*)(e2t + j * NTAG);
#pragma unroll
    for (int q = 0; q < 12; ++q) {
      float4 v = er[q];
      e2[q * 4] = v.x; e2[q * 4 + 1] = v.y; e2[q * 4 + 2] = v.z; e2[q * 4 + 3] = v.w;
    }
  } else {
#pragma unroll
    for (int q = 0; q < NTAG; ++q) e2[q] = 0.f;
  }
  const float* pp = p + ((size_t)b * SEQ) * NTAG + j;
  float A0 = (j < NTAG) ? (startt[j] + pp[0]) * L2E : -3.0e38f;
  float m = A0;
#pragma unroll
  for (int s = 32; s; s >>= 1) m = fmaxf(m, __shfl_xor(m, s));
  float a = (j < NTAG) ? exp2f(A0 - m) : 0.f;
  float acc = m;
  float pv_cur = (j < NTAG && len > 1) ? pp[NTAG] : 0.f;
  float pe_cur = exp2f(pv_cur * L2E);

  for (int t = 1; t < len; ++t) {
    float pv_next = (j < NTAG && t + 1 < len) ? pp[(size_t)(t + 1) * NTAG] : 0.f;
    float pe_next = exp2f(pv_next * L2E);   // independent of the chain; hides
    float c0 = 0.f, c1 = 0.f, c2 = 0.f, c3 = 0.f;
#pragma unroll
    for (int i = 0; i < NTAG; i += 4) {
      c0 = fmaf(__shfl(a, i),     e2[i],     c0);
      c1 = fmaf(__shfl(a, i + 1), e2[i + 1], c1);
      c2 = fmaf(__shfl(a, i + 2), e2[i + 2], c2);
      c3 = fmaf(__shfl(a, i + 3), e2[i + 3], c3);
    }
    float na = (j < NTAG) ? ((c0 + c1) + (c2 + c3)) * pe_cur : 0.f;
    float s = na;
#pragma unroll
    for (int q = 32; q; q >>= 1) s += __shfl_xor(s, q);
    int es = (int)(__float_as_uint(s) >> 23) - 127;        // floor(log2 s)
    float scale = __uint_as_float((uint)(127 - es) << 23); // exact 2^-es
    a = na * scale;
    acc += (float)es;
    pe_cur = pe_next;
  }
  float v = (j < NTAG) ? a * exp2f(endt[j] * L2E) : 0.f;
  float s = v;
#pragma unroll
  for (int q = 32; q; q >>= 1) s += __shfl_xor(s, q);
  if (j == 0) atomicAdd(out, (acc + log2f(s)) * LN2);
}

// ---------------------------------------------------------------- launch
extern "C" void kernel_launch(void* const* d_in, const int* in_sizes, int n_in,
                              void* d_out, int out_size, void* d_ws, size_t ws_size,
                              hipStream_t stream) {
  const int*   tok    = (const int*)d_in[0];
  const int*   slen   = (const int*)d_in[1];
  const int*   lab    = (const int*)d_in[2];
  const float* emb    = (const float*)d_in[3];
  const float* wihf   = (const float*)d_in[4];
  const float* whhf   = (const float*)d_in[5];
  const float* bihf   = (const float*)d_in[6];
  const float* bhhf   = (const float*)d_in[7];
  const float* wihb   = (const float*)d_in[8];
  const float* whhb   = (const float*)d_in[9];
  const float* bihb   = (const float*)d_in[10];
  const float* bhhb   = (const float*)d_in[11];
  const float* wlin   = (const float*)d_in[12];
  const float* blin   = (const float*)d_in[13];
  const float* trans  = (const float*)d_in[14];
  const float* startt = (const float*)d_in[15];
  const float* endt   = (const float*)d_in[16];
  float* out = (float*)d_out;

  char* p = (char*)d_ws;
  ushort* xproj  = (ushort*)p; p += (size_t)NTOK * 2048 * 2;     // 134 MB
  ushort* xb     = (ushort*)p; p += (size_t)NTOK * KPAD * 2;     // 21 MB
  ushort* wb     = (ushort*)p; p += (size_t)2048 * KPAD * 2;     // 1.3 MB
  ushort* hcat   = (ushort*)p; p += (size_t)NTOK * 512 * 2;      // 33.5 MB
  float*  pbuf   = (float*)p;  p += (size_t)NTOK * NTAG * 4;     // 6.3 MB softmax probs
  ushort* wfragL = (ushort*)p; p += (size_t)24576 * 2;           // 48 KB
  float*  bias   = (float*)p;  p += 2048 * 4;
  float*  e2t    = (float*)p;  p += (size_t)NTAG * NTAG * 4;     // 9 KB
  uint*   wq     = (uint*)p;   p += (size_t)2048 * 64 * 4;       // 512 KB
  uint4*  wfrag8 = (uint4*)p;  p += (size_t)32768 * 16;          // 512 KB
  float*  qscale = (float*)p;  p += 2048 * 4;                    // 8 KB

  k_prep_wb    <<<2048, 320, 0, stream>>>(wihf, wihb, wb);
  k_prep_qw    <<<2048, 64, 0, stream>>>(whhf, whhb, wq, qscale);
  k_prep_wfrag8<<<128, 256, 0, stream>>>(wq, wfrag8);
  k_prep_wlt   <<<96, 256, 0, stream>>>(wlin, wfragL);
  k_prep_small <<<1, 256, 0, stream>>>(bihf, bhhf, bihb, bhhb, trans, bias, e2t, out);
  k_gather     <<<NTOK / 4, 256, 0, stream>>>(tok, emb, xb);
  k_gemm       <<<dim3(16, 256), 256, 0, stream>>>(xb, wb, bias, xproj);
  k_rec        <<<64, 512, 0, stream>>>(xproj, wfrag8, qscale, hcat);
  k_lin        <<<NTOK / 128, 256, 0, stream>>>(hcat, wfragL, blin, pbuf);
  k_score      <<<BATCH, 64, 0, stream>>>(pbuf, lab, slen, trans, startt, endt, out);
  k_alpha      <<<BATCH, 64, 0, stream>>>(pbuf, e2t, slen, startt, endt, out);
}

// Round 8
// 1117.440 us; speedup vs baseline: 4.3131x; 1.3161x over previous
//
#include <hip/hip_runtime.h>

// ---------------------------------------------------------------------------
// BiLSTM-CRF fused pipeline for MI355X (gfx950)
// B=64, S=512, V=50000, E=300, H=256 (H2=512), T=48
//   k_rec v4: 64 blocks, W_hh i8 in VGPRs, load-balanced gates.
//   k_lin v3: MFMA GEMM + fused softmax -> p (f32).
//   k_alpha v2: LDS-broadcast matvec (no bpermute), fixed 2^-6 per-step renorm
//               (exact), max-exponent correction every 8 steps.
// ---------------------------------------------------------------------------

using short8 = __attribute__((ext_vector_type(8))) short;
using f32x4  = __attribute__((ext_vector_type(4))) float;
using i32x4  = __attribute__((ext_vector_type(4))) int;
typedef unsigned int  uint;
typedef unsigned short ushort;
typedef unsigned long long ull;

#define BATCH 64
#define SEQ   512
#define EMB   300
#define KPAD  320
#define HID   256
#define NTAG  48
#define NTOK  (BATCH*SEQ)          // 32768

__device__ __forceinline__ float bf2f(ushort u) { return __uint_as_float(((uint)u) << 16); }
__device__ __forceinline__ ushort f2bf(float f) {
  uint u = __float_as_uint(f);
  return (ushort)((u + 0x7fffu + ((u >> 16) & 1u)) >> 16);   // RNE
}
__device__ __forceinline__ uint pk2(float a, float b) {
  return (uint)f2bf(a) | ((uint)f2bf(b) << 16);
}

// ---------------------------------------------------------------- prep kernels
__global__ void k_prep_wb(const float* __restrict__ wihf, const float* __restrict__ wihb,
                          ushort* __restrict__ wb) {
  int n = blockIdx.x;            // 0..2047
  int k = threadIdx.x;           // 0..319
  float v = 0.f;
  if (k < EMB) v = (n < 1024) ? wihf[n * EMB + k] : wihb[(n - 1024) * EMB + k];
  wb[n * KPAD + k] = f2bf(v);
}

// W_hh -> i8 rows + per-row dequant scale (includes s_h = 1/127)
__global__ void k_prep_qw(const float* __restrict__ whhf, const float* __restrict__ whhb,
                          uint* __restrict__ wq, float* __restrict__ qscale) {
  int bx = blockIdx.x;           // 0..2047
  int dir = bx >> 10, n = bx & 1023;
  int l = threadIdx.x;           // 0..63
  const float* W = (dir ? whhb : whhf) + (size_t)n * 256 + l * 4;
  float w0 = W[0], w1 = W[1], w2 = W[2], w3 = W[3];
  float mx = fmaxf(fmaxf(fabsf(w0), fabsf(w1)), fmaxf(fabsf(w2), fabsf(w3)));
#pragma unroll
  for (int s = 32; s; s >>= 1) mx = fmaxf(mx, __shfl_xor(mx, s));
  mx = fmaxf(mx, 1e-30f);
  float inv = 127.f / mx;
  if (l == 0) qscale[dir * 1024 + n] = mx * (1.f / 16129.f);   // (mx/127)*(1/127)
  int q0 = (int)rintf(w0 * inv), q1 = (int)rintf(w1 * inv);
  int q2 = (int)rintf(w2 * inv), q3 = (int)rintf(w3 * inv);
  uint b = ((uint)q0 & 0xffu) | (((uint)q1 & 0xffu) << 8) |
           (((uint)q2 & 0xffu) << 16) | (((uint)q3 & 0xffu) << 24);
  wq[(size_t)(dir * 1024 + n) * 64 + l] = b;
}

// i8 B-fragments, wave-contiguous gatecols
__global__ void k_prep_wfrag8(const uint* __restrict__ wq, uint4* __restrict__ wfrag8) {
  int flat = blockIdx.x * 256 + threadIdx.x;   // < 32768
  int lane = flat & 63;
  int kc   = (flat >> 6) & 3;
  int tile = (flat >> 8) & 7;
  int w    = (flat >> 11) & 7;
  int dir  = flat >> 14;
  int n = w * 128 + tile * 16 + (lane & 15);
  int k0 = kc * 64 + ((lane >> 4) & 3) * 16;
  const uint4* src = (const uint4*)(wq + (size_t)(dir * 1024 + n) * 64 + k0 / 4);
  wfrag8[flat] = *src;
}

// W_lin -> bf16 B-fragments for k_lin
__global__ void k_prep_wlt(const float* __restrict__ wlin, ushort* __restrict__ wfragL) {
  int idx = blockIdx.x * 256 + threadIdx.x;   // < 24576
  int j    = idx & 7;
  int lane = (idx >> 3) & 63;
  int c    = idx >> 9;              // kk*3+nt, 0..47
  int nt = c % 3, kk = c / 3;
  int tag = nt * 16 + (lane & 15);
  int k   = kk * 32 + (lane >> 4) * 8 + j;
  wfragL[idx] = f2bf(wlin[tag * 512 + k]);
}

// bias fold + out init + E2T[j][i] = 2^(T[i][j]*log2e)
__global__ void k_prep_small(const float* __restrict__ bihf, const float* __restrict__ bhhf,
                             const float* __restrict__ bihb, const float* __restrict__ bhhb,
                             const float* __restrict__ trans,
                             float* __restrict__ bias, float* __restrict__ e2t,
                             float* __restrict__ out) {
  int tid = threadIdx.x;
  if (tid == 0) out[0] = 0.f;
  for (int i = tid; i < 2048; i += 256)
    bias[i] = (i < 1024) ? (bihf[i] + bhhf[i]) : (bihb[i - 1024] + bhhb[i - 1024]);
  const float L2E = 1.4426950408889634f;
  for (int idx = tid; idx < NTAG * NTAG; idx += 256) {
    int j = idx / NTAG, i = idx - j * NTAG;
    e2t[j * NTAG + i] = exp2f(trans[i * NTAG + j] * L2E);
  }
}

// ---------------------------------------------------------------- gather
__global__ __launch_bounds__(256) void k_gather(const int* __restrict__ tok,
                                                const float* __restrict__ emb,
                                                ushort* __restrict__ xb) {
  int r = blockIdx.x * 4 + (threadIdx.x >> 6);   // token row, < 32768
  int l = threadIdx.x & 63;
  int t = tok[r];
  const float* e = emb + (size_t)t * EMB;
  ushort* xr = xb + (size_t)r * KPAD;
#pragma unroll
  for (int q = 0; q < 5; ++q) {
    int k = l + q * 64;
    xr[k] = f2bf((k < EMB) ? e[k] : 0.f);
  }
}

// ---------------------------------------------------------------- input-proj GEMM
__global__ __launch_bounds__(256) void k_gemm(const ushort* __restrict__ xb,
                                              const ushort* __restrict__ wb,
                                              const float* __restrict__ bias,
                                              ushort* __restrict__ xproj) {
  __shared__ __align__(16) ushort Asm[128 * 64];
  __shared__ __align__(16) ushort Bsm[128 * 64];
  const int tid = threadIdx.x;
  const int w = tid >> 6, l = tid & 63;
  const int m0 = blockIdx.y * 128, n0 = blockIdx.x * 128;
  const int wr = (w >> 1) * 64, wc = (w & 1) * 64;
  f32x4 acc[4][4] = {};

  for (int kt = 0; kt < 5; ++kt) {
    const int k0 = kt * 64;
    short8 va[4], vb[4];
#pragma unroll
    for (int i = 0; i < 4; ++i) {
      int cid = tid + 256 * i;
      int row = cid >> 3, slot = cid & 7;
      va[i] = *(const short8*)(xb + (size_t)(m0 + row) * KPAD + k0 + slot * 8);
      vb[i] = *(const short8*)(wb + (size_t)(n0 + row) * KPAD + k0 + slot * 8);
    }
    __syncthreads();
#pragma unroll
    for (int i = 0; i < 4; ++i) {
      int cid = tid + 256 * i;
      int row = cid >> 3, slot = cid & 7;
      int sw = (slot ^ (row & 7)) * 8;
      *(short8*)(&Asm[row * 64 + sw]) = va[i];
      *(short8*)(&Bsm[row * 64 + sw]) = vb[i];
    }
    __syncthreads();
#pragma unroll
    for (int kk = 0; kk < 2; ++kk) {
      int ks = (l >> 4) + kk * 4;
      short8 af[4], bfr[4];
#pragma unroll
      for (int mt = 0; mt < 4; ++mt) {
        int row = wr + mt * 16 + (l & 15);
        af[mt] = *(const short8*)(&Asm[row * 64 + ((ks ^ (row & 7)) * 8)]);
      }
#pragma unroll
      for (int nt = 0; nt < 4; ++nt) {
        int row = wc + nt * 16 + (l & 15);
        bfr[nt] = *(const short8*)(&Bsm[row * 64 + ((ks ^ (row & 7)) * 8)]);
      }
#pragma unroll
      for (int mt = 0; mt < 4; ++mt)
#pragma unroll
        for (int nt = 0; nt < 4; ++nt)
          acc[mt][nt] = __builtin_amdgcn_mfma_f32_16x16x32_bf16(af[mt], bfr[nt], acc[mt][nt], 0, 0, 0);
    }
  }
#pragma unroll
  for (int nt = 0; nt < 4; ++nt) {
    int n = n0 + wc + nt * 16 + (l & 15);
    float bv = bias[n];
#pragma unroll
    for (int mt = 0; mt < 4; ++mt) {
      int rbase = m0 + wr + mt * 16 + ((l >> 4) * 4);
#pragma unroll
      for (int r = 0; r < 4; ++r)
        xproj[(size_t)(rbase + r) * 2048 + n] = f2bf(acc[mt][nt][r] + bv);
    }
  }
}

// ---------------------------------------------------------------- recurrent LSTM
__global__ __launch_bounds__(512, 2) void k_rec(const ushort* __restrict__ xproj,
                                                const uint4* __restrict__ wfrag8,
                                                const float* __restrict__ qscale,
                                                ushort* __restrict__ hcat) {
  const int blk = blockIdx.x;
  const int dir = blk & 1, chunk = blk >> 1;   // chunk 0..31
  const int bb = chunk * 2;
  const int tid = threadIdx.x, w = tid >> 6, l = tid & 63;
  __shared__ __align__(16) char hlds[2][16 * 256];
  __shared__ __align__(16) int  zlds[2][1024];

  i32x4 wfr[8][4];
  {
    const uint4* wp = wfrag8 + (size_t)(dir * 8 + w) * 2048 + l;
#pragma unroll
    for (int tile = 0; tile < 8; ++tile)
#pragma unroll
      for (int kc = 0; kc < 4; ++kc) {
        union { uint4 u; i32x4 v; } cc;
        cc.u = wp[(tile * 4 + kc) * 64];
        wfr[tile][kc] = cc.v;
      }
  }
  const int row  = tid >> 8;        // 0..1
  const int unit = tid & 255;
  float qs4[4];
#pragma unroll
  for (int g = 0; g < 4; ++g) qs4[g] = qscale[dir * 1024 + g * 256 + unit];

  ((uint4*)hlds)[tid] = uint4{0u, 0u, 0u, 0u};
  __syncthreads();

  const int tt0 = dir ? (SEQ - 1) : 0;
  const ptrdiff_t dstep = dir ? -2048 : 2048;
  const ushort* xp = xproj + ((size_t)(bb + row) * SEQ + tt0) * 2048 + dir * 1024 + unit;
  ushort xs[4];
#pragma unroll
  for (int g = 0; g < 4; ++g) xs[g] = xp[g * 256];
  float c = 0.f;
  int tt = tt0;

  for (int t = 0; t < SEQ; ++t) {
    ushort xn[4] = {0, 0, 0, 0};
    if (t + 1 < SEQ) {
      const ushort* xpn = xp + dstep;
#pragma unroll
      for (int g = 0; g < 4; ++g) xn[g] = xpn[g * 256];
    }

    if (t > 0) {
      const char* hs = hlds[(t - 1) & 1];
      const int r16 = l & 15;
      i32x4 a[4];
#pragma unroll
      for (int kc = 0; kc < 4; ++kc) {
        int gr = kc * 4 + (l >> 4);
        a[kc] = *(const i32x4*)(hs + r16 * 256 + ((gr ^ r16) & 15) * 16);
      }
      i32x4 acc[8] = {};
#pragma unroll
      for (int tile = 0; tile < 8; ++tile)
#pragma unroll
        for (int kc = 0; kc < 4; ++kc)
          acc[tile] = __builtin_amdgcn_mfma_i32_16x16x64_i8(a[kc], wfr[tile][kc], acc[tile], 0, 0, 0);
      if (l < 16) {
#pragma unroll
        for (int tile = 0; tile < 8; ++tile) {
          const int col = w * 128 + tile * 16 + l;
          zlds[0][col] = acc[tile][0];
          zlds[1][col] = acc[tile][1];
        }
      }
    }
    __syncthreads();   // z ready

    float zf[4];
#pragma unroll
    for (int g = 0; g < 4; ++g) {
      float zi = (t > 0) ? (float)zlds[row][g * 256 + unit] * qs4[g] : 0.f;
      zf[g] = zi + bf2f(xs[g]);
    }
    float ig = 1.f / (1.f + __expf(-zf[0]));
    float fg = 1.f / (1.f + __expf(-zf[1]));
    float gg = 2.f / (1.f + __expf(-2.f * zf[2])) - 1.f;
    float og = 1.f / (1.f + __expf(-zf[3]));
    c = fg * c + ig * gg;
    float hv = og * (2.f / (1.f + __expf(-2.f * c)) - 1.f);
    hcat[((size_t)(bb + row) * SEQ + tt) * 512 + dir * 256 + unit] = f2bf(hv);

    int hq = (int)rintf(hv * 127.f);
    uint v  = (uint)hq & 0xffu;
    uint x1 = __shfl_xor(v, 1);
    uint v2 = __builtin_amdgcn_perm(x1, v, (l & 1) ? 0x00000004u : 0x00000400u);
    uint x2 = __shfl_xor(v2, 2);
    uint v4 = __builtin_amdgcn_perm(x2, v2, (l & 2) ? 0x01000504u : 0x05040100u);
    if (!(l & 3)) {
      const int u0 = unit & ~3;
      *(uint*)(&hlds[t & 1][row * 256 + (((u0 >> 4) ^ row) & 15) * 16 + (u0 & 15)]) = v4;
    }
    __syncthreads();   // h(t) visible, z consumed

#pragma unroll
    for (int g = 0; g < 4; ++g) xs[g] = xn[g];
    xp += dstep;
    tt += dir ? -1 : 1;
  }
}

// ---------------------------------------------------------------- output linear (MFMA) + fused softmax
__global__ __launch_bounds__(256) void k_lin(const ushort* __restrict__ hcat,
                                             const ushort* __restrict__ wfragL,
                                             const float* __restrict__ blin,
                                             float* __restrict__ p) {
  __shared__ __align__(16) ushort Asm[128 * 64];
  const int tid = threadIdx.x;
  const int w = tid >> 6, l = tid & 63;
  const size_t m0 = (size_t)blockIdx.x * 128;
  const float L2E = 1.4426950408889634f;
  f32x4 acc[2][3] = {};

  for (int kb = 0; kb < 8; ++kb) {        // BK = 64
    short8 va[4];
#pragma unroll
    for (int i = 0; i < 4; ++i) {
      int cid = tid + 256 * i;
      int row = cid >> 3, slot = cid & 7;
      va[i] = *(const short8*)(hcat + (m0 + row) * 512 + kb * 64 + slot * 8);
    }
    __syncthreads();
#pragma unroll
    for (int i = 0; i < 4; ++i) {
      int cid = tid + 256 * i;
      int row = cid >> 3, slot = cid & 7;
      *(short8*)(&Asm[row * 64 + ((slot ^ (row & 7)) * 8)]) = va[i];
    }
    __syncthreads();
#pragma unroll
    for (int kk = 0; kk < 2; ++kk) {
      int ks = (l >> 4) + kk * 4;
      short8 af[2], bfr[3];
#pragma unroll
      for (int mt = 0; mt < 2; ++mt) {
        int row = (w * 2 + mt) * 16 + (l & 15);
        af[mt] = *(const short8*)(&Asm[row * 64 + ((ks ^ (row & 7)) * 8)]);
      }
#pragma unroll
      for (int nt = 0; nt < 3; ++nt)
        bfr[nt] = *(const short8*)(wfragL + (size_t)(((kb * 2 + kk) * 3 + nt) * 64 + l) * 8);
#pragma unroll
      for (int mt = 0; mt < 2; ++mt)
#pragma unroll
        for (int nt = 0; nt < 3; ++nt)
          acc[mt][nt] = __builtin_amdgcn_mfma_f32_16x16x32_bf16(af[mt], bfr[nt], acc[mt][nt], 0, 0, 0);
    }
  }
  float bl0 = blin[l & 15], bl1 = blin[16 + (l & 15)], bl2 = blin[32 + (l & 15)];
#pragma unroll
  for (int mt = 0; mt < 2; ++mt) {
#pragma unroll
    for (int r = 0; r < 4; ++r) {
      size_t row = m0 + (w * 2 + mt) * 16 + (l >> 4) * 4 + r;
      float v0 = acc[mt][0][r] + bl0;
      float v1 = acc[mt][1][r] + bl1;
      float v2 = acc[mt][2][r] + bl2;
      float mx = fmaxf(fmaxf(v0, v1), v2);
#pragma unroll
      for (int s = 8; s; s >>= 1) mx = fmaxf(mx, __shfl_xor(mx, s));
      float e0 = exp2f((v0 - mx) * L2E);
      float e1 = exp2f((v1 - mx) * L2E);
      float e2 = exp2f((v2 - mx) * L2E);
      float ssum = e0 + e1 + e2;
#pragma unroll
      for (int s = 8; s; s >>= 1) ssum += __shfl_xor(ssum, s);
      float inv = 1.f / ssum;
      p[row * NTAG +      (l & 15)] = e0 * inv;
      p[row * NTAG + 16 + (l & 15)] = e1 * inv;
      p[row * NTAG + 32 + (l & 15)] = e2 * inv;
    }
  }
}

// ---------------------------------------------------------------- CRF numerator (parallel)
__global__ __launch_bounds__(64) void k_score(const float* __restrict__ p,
                                              const int* __restrict__ labels,
                                              const int* __restrict__ slen,
                                              const float* __restrict__ trans,
                                              const float* __restrict__ startt,
                                              const float* __restrict__ endt,
                                              float* __restrict__ out) {
  const int b = blockIdx.x, l = threadIdx.x;
  int len = slen[b]; len = (len < 1) ? 1 : (len > SEQ ? SEQ : len);
  const int* tg = labels + (size_t)b * SEQ;
  float part = 0.f;
  for (int t = l; t < len; t += 64) {
    int tag = tg[t];
    part += p[((size_t)b * SEQ + t) * NTAG + tag];
    if (t >= 1)       part += trans[tg[t - 1] * NTAG + tag];
    if (t == 0)       part += startt[tag];
    if (t == len - 1) part += endt[tag];
  }
#pragma unroll
  for (int s = 32; s; s >>= 1) part += __shfl_xor(part, s);
  if (l == 0) atomicAdd(out, -part);
}

// ---------------------------------------------------------------- CRF forward v2
// LDS-broadcast matvec; fixed 2^-6/step renorm (exact) + 8-step drift fix.
__global__ __launch_bounds__(64) void k_alpha(const float* __restrict__ p,
                                              const float* __restrict__ e2t,
                                              const int* __restrict__ slen,
                                              const float* __restrict__ startt,
                                              const float* __restrict__ endt,
                                              float* __restrict__ out) {
  const int b = blockIdx.x, j = threadIdx.x;
  const float L2E = 1.4426950408889634f, LN2 = 0.6931471805599453f;
  __shared__ __align__(16) float alds[64];
  int len = slen[b]; len = (len < 1) ? 1 : (len > SEQ ? SEQ : len);
  float e2[NTAG];
  if (j < NTAG) {
    const float4* er = (const float4*)(e2t + j * NTAG);
#pragma unroll
    for (int q = 0; q < 12; ++q) {
      float4 v = er[q];
      e2[q * 4] = v.x; e2[q * 4 + 1] = v.y; e2[q * 4 + 2] = v.z; e2[q * 4 + 3] = v.w;
    }
  } else {
#pragma unroll
    for (int q = 0; q < NTAG; ++q) e2[q] = 0.f;
  }
  const float* pp = p + ((size_t)b * SEQ) * NTAG + j;
  float A0 = (j < NTAG) ? (startt[j] + pp[0]) * L2E : -3.0e38f;
  float m = A0;
#pragma unroll
  for (int s = 32; s; s >>= 1) m = fmaxf(m, __shfl_xor(m, s));
  float a = (j < NTAG) ? exp2f(A0 - m) : 0.f;
  float acc = m + 6.0f * (float)(len - 1);      // fixed 2^-6/step, hoisted
  alds[j] = a;
  float pv_cur = (j < NTAG && len > 1) ? pp[NTAG] : 0.f;
  float pe_cur = exp2f(pv_cur * L2E);

  for (int t = 1; t < len; ++t) {
    float pv_next = (j < NTAG && t + 1 < len) ? pp[(size_t)(t + 1) * NTAG] : 0.f;
    float pe_next = exp2f(pv_next * L2E);       // off the critical chain
    float4 av[12];
#pragma unroll
    for (int q = 0; q < 12; ++q) av[q] = *(const float4*)&alds[q * 4];   // broadcast reads
    float c0 = 0.f, c1 = 0.f, c2 = 0.f, c3 = 0.f;
#pragma unroll
    for (int q = 0; q < 12; ++q) {
      c0 = fmaf(av[q].x, e2[q * 4],     c0);
      c1 = fmaf(av[q].y, e2[q * 4 + 1], c1);
      c2 = fmaf(av[q].z, e2[q * 4 + 2], c2);
      c3 = fmaf(av[q].w, e2[q * 4 + 3], c3);
    }
    float na = ((c0 + c1) + (c2 + c3)) * pe_cur * 0.015625f;   // exact 2^-6
    if ((t & 7) == 0) {                          // periodic drift correction
      float mx = na;
#pragma unroll
      for (int s = 32; s; s >>= 1) mx = fmaxf(mx, __shfl_xor(mx, s));
      int es = (int)(__float_as_uint(mx) >> 23) - 127;
      na *= __uint_as_float((uint)(127 - es) << 23);           // exact 2^-es
      acc += (float)es;
    }
    alds[j] = na;
    pe_cur = pe_next;
  }
  float av_end = (j < NTAG) ? alds[j] * exp2f(endt[j] * L2E) : 0.f;
  float s = av_end;
#pragma unroll
  for (int q = 32; q; q >>= 1) s += __shfl_xor(s, q);
  if (j == 0) atomicAdd(out, (acc + log2f(s)) * LN2);
}

// ---------------------------------------------------------------- launch
extern "C" void kernel_launch(void* const* d_in, const int* in_sizes, int n_in,
                              void* d_out, int out_size, void* d_ws, size_t ws_size,
                              hipStream_t stream) {
  const int*   tok    = (const int*)d_in[0];
  const int*   slen   = (const int*)d_in[1];
  const int*   lab    = (const int*)d_in[2];
  const float* emb    = (const float*)d_in[3];
  const float* wihf   = (const float*)d_in[4];
  const float* whhf   = (const float*)d_in[5];
  const float* bihf   = (const float*)d_in[6];
  const float* bhhf   = (const float*)d_in[7];
  const float* wihb   = (const float*)d_in[8];
  const float* whhb   = (const float*)d_in[9];
  const float* bihb   = (const float*)d_in[10];
  const float* bhhb   = (const float*)d_in[11];
  const float* wlin   = (const float*)d_in[12];
  const float* blin   = (const float*)d_in[13];
  const float* trans  = (const float*)d_in[14];
  const float* startt = (const float*)d_in[15];
  const float* endt   = (const float*)d_in[16];
  float* out = (float*)d_out;

  char* p = (char*)d_ws;
  ushort* xproj  = (ushort*)p; p += (size_t)NTOK * 2048 * 2;     // 134 MB
  ushort* xb     = (ushort*)p; p += (size_t)NTOK * KPAD * 2;     // 21 MB
  ushort* wb     = (ushort*)p; p += (size_t)2048 * KPAD * 2;     // 1.3 MB
  ushort* hcat   = (ushort*)p; p += (size_t)NTOK * 512 * 2;      // 33.5 MB
  float*  pbuf   = (float*)p;  p += (size_t)NTOK * NTAG * 4;     // 6.3 MB softmax probs
  ushort* wfragL = (ushort*)p; p += (size_t)24576 * 2;           // 48 KB
  float*  bias   = (float*)p;  p += 2048 * 4;
  float*  e2t    = (float*)p;  p += (size_t)NTAG * NTAG * 4;     // 9 KB
  uint*   wq     = (uint*)p;   p += (size_t)2048 * 64 * 4;       // 512 KB
  uint4*  wfrag8 = (uint4*)p;  p += (size_t)32768 * 16;          // 512 KB
  float*  qscale = (float*)p;  p += 2048 * 4;                    // 8 KB

  k_prep_wb    <<<2048, 320, 0, stream>>>(wihf, wihb, wb);
  k_prep_qw    <<<2048, 64, 0, stream>>>(whhf, whhb, wq, qscale);
  k_prep_wfrag8<<<128, 256, 0, stream>>>(wq, wfrag8);
  k_prep_wlt   <<<96, 256, 0, stream>>>(wlin, wfragL);
  k_prep_small <<<1, 256, 0, stream>>>(bihf, bhhf, bihb, bhhb, trans, bias, e2t, out);
  k_gather     <<<NTOK / 4, 256, 0, stream>>>(tok, emb, xb);
  k_gemm       <<<dim3(16, 256), 256, 0, stream>>>(xb, wb, bias, xproj);
  k_rec        <<<64, 512, 0, stream>>>(xproj, wfrag8, qscale, hcat);
  k_lin        <<<NTOK / 128, 256, 0, stream>>>(hcat, wfragL, blin, pbuf);
  k_score      <<<BATCH, 64, 0, stream>>>(pbuf, lab, slen, trans, startt, endt, out);
  k_alpha      <<<BATCH, 64, 0, stream>>>(pbuf, e2t, slen, startt, endt, out);
}